// Round 1
// baseline (2497.244 us; speedup 1.0000x reference)
//
#include <hip/hip_runtime.h>
#include <hip/hip_bf16.h>
#include <float.h>
#include <math.h>

#define NB 8
#define CCH 384
#define NHEAD 6
#define DHEAD 64
#define AAD 48
#define MSEG 1024
#define NSUP 6
#define NTOK 8200
#define NFEAT 8192
#define SEG2 1536

// feat row n (0..8191) -> row index in (B,1025,C) token array, skipping CLS
static __device__ __forceinline__ long long tokrow(int n) {
  return (long long)n + (n >> 10) + 1;
}

template<int NT>
static __device__ __forceinline__ float block_reduce_sum(float v, float* s) {
  #pragma unroll
  for (int off = 32; off > 0; off >>= 1) v += __shfl_down(v, off, 64);
  int lane = threadIdx.x & 63, wid = threadIdx.x >> 6;
  if (lane == 0) s[wid] = v;
  __syncthreads();
  if (threadIdx.x == 0) {
    float t = s[0];
    #pragma unroll
    for (int w = 1; w < NT / 64; w++) t += s[w];
    s[0] = t;
  }
  __syncthreads();
  float r = s[0];
  __syncthreads();
  return r;
}

template<int NT>
static __device__ __forceinline__ float block_reduce_max(float v, float* s) {
  #pragma unroll
  for (int off = 32; off > 0; off >>= 1) v = fmaxf(v, __shfl_down(v, off, 64));
  int lane = threadIdx.x & 63, wid = threadIdx.x >> 6;
  if (lane == 0) s[wid] = v;
  __syncthreads();
  if (threadIdx.x == 0) {
    float t = s[0];
    #pragma unroll
    for (int w = 1; w < NT / 64; w++) t = fmaxf(t, s[w]);
    s[0] = t;
  }
  __syncthreads();
  float r = s[0];
  __syncthreads();
  return r;
}

static __device__ __forceinline__ void atomicMaxFloat(float* addr, float val) {
  if (val >= 0.f) atomicMax((int*)addr, __float_as_int(val));
  else            atomicMin((unsigned int*)addr, __float_as_uint(val));
}

// ---------------------------------------------------------------------------
// Generic tiled GEMM.  TRANS_B=true : C[m,n] = sum_k A[m,k] * B[n,k]
//                      TRANS_B=false: C[m,n] = sum_k A[m,k] * B[k,n]
// Epilogue: v = act(acc + bias[n]); v *= scale * rowmask[m];
//           v += res1[(skip?tokrow(m):m), n]; v += res2[m, n];  C = v
// avec/bvec: caller certifies float4-aligned loads with K%16==0 (A) / guards.
// ---------------------------------------------------------------------------
template<bool TRANS_B>
__global__ __launch_bounds__(256) void gemm_kernel(
    const float* __restrict__ A, long long lda, long long sA, int avec,
    const float* __restrict__ B, long long ldb, long long sB, int bvec,
    float* __restrict__ C, long long ldc, long long sC,
    int Mr, int Nc, int Kd,
    const float* __restrict__ bias, int act, float scale,
    const float* __restrict__ rowmask,
    const float* __restrict__ res1, long long ldr1, int res1_skip,
    const float* __restrict__ res2, long long ldr2)
{
  __shared__ float As[16][68];
  __shared__ float Bs[16][68];
  const float* Ap = A + (long long)blockIdx.z * sA;
  const float* Bp = B + (long long)blockIdx.z * sB;
  float*       Cp = C + (long long)blockIdx.z * sC;
  const int m0 = blockIdx.y * 64, n0 = blockIdx.x * 64;
  const int tid = threadIdx.x;
  const int tx = tid & 15, ty = tid >> 4;
  float acc[4][4] = {{0.f, 0.f, 0.f, 0.f}, {0.f, 0.f, 0.f, 0.f},
                     {0.f, 0.f, 0.f, 0.f}, {0.f, 0.f, 0.f, 0.f}};

  for (int k0 = 0; k0 < Kd; k0 += 16) {
    { // stage A tile (64 rows x 16 k) into As[k][m]
      int row = tid >> 2, k4 = (tid & 3) << 2;
      int gm = m0 + row, gk = k0 + k4;
      float v0 = 0.f, v1 = 0.f, v2 = 0.f, v3 = 0.f;
      if (gm < Mr) {
        const float* p = Ap + (long long)gm * lda;
        if (avec) {
          float4 v = *(const float4*)(p + gk);
          v0 = v.x; v1 = v.y; v2 = v.z; v3 = v.w;
        } else {
          if (gk + 0 < Kd) v0 = p[gk + 0];
          if (gk + 1 < Kd) v1 = p[gk + 1];
          if (gk + 2 < Kd) v2 = p[gk + 2];
          if (gk + 3 < Kd) v3 = p[gk + 3];
        }
      }
      As[k4 + 0][row] = v0; As[k4 + 1][row] = v1;
      As[k4 + 2][row] = v2; As[k4 + 3][row] = v3;
    }
    if (TRANS_B) { // B is (N,K): stage into Bs[k][n]
      int row = tid >> 2, k4 = (tid & 3) << 2;
      int gn = n0 + row, gk = k0 + k4;
      float v0 = 0.f, v1 = 0.f, v2 = 0.f, v3 = 0.f;
      if (gn < Nc) {
        const float* p = Bp + (long long)gn * ldb;
        if (bvec) {
          float4 v = *(const float4*)(p + gk);
          v0 = v.x; v1 = v.y; v2 = v.z; v3 = v.w;
        } else {
          if (gk + 0 < Kd) v0 = p[gk + 0];
          if (gk + 1 < Kd) v1 = p[gk + 1];
          if (gk + 2 < Kd) v2 = p[gk + 2];
          if (gk + 3 < Kd) v3 = p[gk + 3];
        }
      }
      Bs[k4 + 0][row] = v0; Bs[k4 + 1][row] = v1;
      Bs[k4 + 2][row] = v2; Bs[k4 + 3][row] = v3;
    } else { // B is (K,N): stage into Bs[k][n]
      int krow = tid >> 4, n4 = (tid & 15) << 2;
      int gk = k0 + krow, gn = n0 + n4;
      float v0 = 0.f, v1 = 0.f, v2 = 0.f, v3 = 0.f;
      if (gk < Kd) {
        const float* p = Bp + (long long)gk * ldb;
        if (bvec && gn + 3 < Nc) {
          float4 v = *(const float4*)(p + gn);
          v0 = v.x; v1 = v.y; v2 = v.z; v3 = v.w;
        } else {
          if (gn + 0 < Nc) v0 = p[gn + 0];
          if (gn + 1 < Nc) v1 = p[gn + 1];
          if (gn + 2 < Nc) v2 = p[gn + 2];
          if (gn + 3 < Nc) v3 = p[gn + 3];
        }
      }
      Bs[krow][n4 + 0] = v0; Bs[krow][n4 + 1] = v1;
      Bs[krow][n4 + 2] = v2; Bs[krow][n4 + 3] = v3;
    }
    __syncthreads();
    int kmax = Kd - k0; if (kmax > 16) kmax = 16;
    if (kmax == 16) {
      #pragma unroll
      for (int k = 0; k < 16; k++) {
        float4 a4 = *(const float4*)&As[k][ty << 2];
        float4 b4 = *(const float4*)&Bs[k][tx << 2];
        float a[4] = {a4.x, a4.y, a4.z, a4.w};
        float b[4] = {b4.x, b4.y, b4.z, b4.w};
        #pragma unroll
        for (int i = 0; i < 4; i++)
          #pragma unroll
          for (int j = 0; j < 4; j++) acc[i][j] = fmaf(a[i], b[j], acc[i][j]);
      }
    } else {
      for (int k = 0; k < kmax; k++) {
        float4 a4 = *(const float4*)&As[k][ty << 2];
        float4 b4 = *(const float4*)&Bs[k][tx << 2];
        float a[4] = {a4.x, a4.y, a4.z, a4.w};
        float b[4] = {b4.x, b4.y, b4.z, b4.w};
        #pragma unroll
        for (int i = 0; i < 4; i++)
          #pragma unroll
          for (int j = 0; j < 4; j++) acc[i][j] = fmaf(a[i], b[j], acc[i][j]);
      }
    }
    __syncthreads();
  }

  #pragma unroll
  for (int i = 0; i < 4; i++) {
    int gm = m0 + (ty << 2) + i;
    if (gm >= Mr) continue;
    float rm = rowmask ? rowmask[gm] : 1.0f;
    #pragma unroll
    for (int j = 0; j < 4; j++) {
      int gn = n0 + (tx << 2) + j;
      if (gn >= Nc) continue;
      float v = acc[i][j];
      if (bias) v += bias[gn];
      if (act == 1) v = v / (1.0f + __expf(-1.702f * v));  // quick_gelu
      v *= scale * rm;
      if (res1) {
        long long rr = res1_skip ? tokrow(gm) : (long long)gm;
        v += res1[rr * ldr1 + gn];
      }
      if (res2) v += res2[(long long)gm * ldr2 + gn];
      Cp[(long long)gm * ldc + gn] = v;
    }
  }
}

// LayerNorm over C=384, one block per row; skipcls remaps to non-CLS token rows
__global__ __launch_bounds__(128) void ln_kernel(
    const float* __restrict__ in, float* __restrict__ out,
    const float* __restrict__ g, const float* __restrict__ b, int skipcls)
{
  int r = blockIdx.x;
  long long ir = skipcls ? tokrow(r) : (long long)r;
  const float* x = in + ir * CCH;
  __shared__ float sb[2];
  int c = threadIdx.x;
  float v0 = x[c], v1 = x[c + 128], v2 = x[c + 256];
  float s  = block_reduce_sum<128>(v0 + v1 + v2, sb);
  float s2 = block_reduce_sum<128>(v0 * v0 + v1 * v1 + v2 * v2, sb);
  float m = s * (1.0f / CCH);
  float var = s2 * (1.0f / CCH) - m * m;
  float rstd = rsqrtf(var + 1e-5f);
  float* o = out + (long long)r * CCH;
  o[c]       = (v0 - m) * rstd * g[c]       + b[c];
  o[c + 128] = (v1 - m) * rstd * g[c + 128] + b[c + 128];
  o[c + 256] = (v2 - m) * rstd * g[c + 256] + b[c + 256];
}

// softmax over rows of length 1025 with logit scale 1/8, in place
__global__ __launch_bounds__(256) void softmax_kernel(float* __restrict__ S)
{
  long long r = blockIdx.x;
  float* p = S + r * 1025;
  int tid = threadIdx.x;
  float vals[5];
  float lm = -FLT_MAX;
  #pragma unroll
  for (int e = 0; e < 5; e++) {
    int c = tid + e * 256;
    vals[e] = (c < 1025) ? p[c] : -FLT_MAX;
    lm = fmaxf(lm, vals[e]);
  }
  __shared__ float sb[4];
  float m = block_reduce_max<256>(lm, sb);
  float ls = 0.f;
  #pragma unroll
  for (int e = 0; e < 5; e++) {
    int c = tid + e * 256;
    if (c < 1025) { vals[e] = __expf(0.125f * (vals[e] - m)); ls += vals[e]; }
  }
  float s = block_reduce_sum<256>(ls, sb);
  float inv = 1.0f / s;
  #pragma unroll
  for (int e = 0; e < 5; e++) {
    int c = tid + e * 256;
    if (c < 1025) p[c] = vals[e] * inv;
  }
}

// sorted-segment max+mean over cluster ids; one block per segment
__global__ __launch_bounds__(128) void seg1_kernel(
    const float* __restrict__ x2, const int* __restrict__ sorted_idx,
    const int* __restrict__ seg_id, float* __restrict__ s3)
{
  int s = blockIdx.x;
  int lo = 0, hi = NFEAT;
  while (lo < hi) { int mid = (lo + hi) >> 1; if (seg_id[mid] < s) lo = mid + 1; else hi = mid; }
  int start = lo;
  hi = NFEAT;
  while (lo < hi) { int mid = (lo + hi) >> 1; if (seg_id[mid] < s + 1) lo = mid + 1; else hi = mid; }
  int end = lo;
  int cnt = end - start;
  for (int c = threadIdx.x; c < CCH; c += 128) {
    float sum = 0.f, mx = -FLT_MAX;
    for (int r = start; r < end; r++) {
      int n = sorted_idx[r];
      float v = x2[tokrow(n) * CCH + c];
      sum += v; mx = fmaxf(mx, v);
    }
    float u = (cnt > 0 ? mx : 0.f) + sum / fmaxf((float)cnt, 1.0f);
    s3[(long long)s * CCH + c] = u;
  }
}

// per-channel batchnorm stats over `rows` rows
__global__ __launch_bounds__(256) void bnstats_kernel(
    const float* __restrict__ u, int rows,
    float* __restrict__ mean, float* __restrict__ var)
{
  int c = blockIdx.x;
  float s = 0.f, s2 = 0.f;
  for (int r = threadIdx.x; r < rows; r += 256) {
    float v = u[(long long)r * CCH + c];
    s += v; s2 += v * v;
  }
  __shared__ float sb[4];
  s  = block_reduce_sum<256>(s, sb);
  s2 = block_reduce_sum<256>(s2, sb);
  if (threadIdx.x == 0) {
    float m = s / rows;
    mean[c] = m;
    var[c] = s2 / rows - m * m;
  }
}

// apply BN + exact gelu, store result and row L2 norm; one block per row
__global__ __launch_bounds__(128) void bnapply_kernel(
    const float* __restrict__ u,
    const float* __restrict__ mean, const float* __restrict__ var,
    const float* __restrict__ g, const float* __restrict__ b,
    float* __restrict__ t, float* __restrict__ norms)
{
  int r = blockIdx.x;
  float ss = 0.f;
  #pragma unroll
  for (int e = 0; e < 3; e++) {
    int c = threadIdx.x + e * 128;
    float v = u[(long long)r * CCH + c];
    float y = (v - mean[c]) * rsqrtf(var[c] + 1e-5f) * g[c] + b[c];
    float ge = 0.5f * y * (1.0f + erff(y * 0.70710678118654752f));
    t[(long long)r * CCH + c] = ge;
    ss += ge * ge;
  }
  __shared__ float sb[2];
  ss = block_reduce_sum<128>(ss, sb);
  if (threadIdx.x == 0) norms[r] = sqrtf(ss);
}

__global__ void seginit_kernel(float* sum, float* mx, float* cnt)
{
  int idx = blockIdx.x * 256 + threadIdx.x;
  if (idx < SEG2 * CCH) { sum[idx] = 0.f; mx[idx] = -FLT_MAX; }
  if (idx < SEG2) cnt[idx] = 0.f;
}

__global__ __launch_bounds__(128) void scatter_kernel(
    const float* __restrict__ fx, const int* __restrict__ fgi,
    float* __restrict__ sum, float* __restrict__ mx, float* __restrict__ cnt)
{
  int n = blockIdx.x;
  int s = fgi[n];
  const float* row = fx + (long long)n * CCH;
  float* ps = sum + (long long)s * CCH;
  float* pm = mx + (long long)s * CCH;
  for (int c = threadIdx.x; c < CCH; c += 128) {
    float v = row[c];
    atomicAdd(ps + c, v);
    atomicMaxFloat(pm + c, v);
  }
  if (threadIdx.x == 0) atomicAdd(cnt + s, 1.0f);
}

// sum <- (cnt>0 ? max : 0) + sum / max(cnt,1), in place
__global__ void segcombine_kernel(float* __restrict__ sum,
                                  const float* __restrict__ mx,
                                  const float* __restrict__ cnt)
{
  int idx = blockIdx.x * 256 + threadIdx.x;
  if (idx >= SEG2 * CCH) return;
  int r = idx / CCH;
  float c = cnt[r];
  float m = (c > 0.f) ? mx[idx] : 0.f;
  sum[idx] = m + sum[idx] / fmaxf(c, 1.0f);
}

// cosine-sim weighting + final output (handles CLS copy too)
__global__ __launch_bounds__(128) void final_kernel(
    const float* __restrict__ x2, const float* __restrict__ t3,
    const float* __restrict__ t3norm, const float* __restrict__ t1d,
    const float* __restrict__ t1dnorm, const int* __restrict__ cluster,
    const int* __restrict__ fgi, float* __restrict__ out)
{
  int row = blockIdx.x;                    // 0..8199: b*1025+gg
  int b = row / 1025, gg = row - b * 1025;
  const float* xr = x2 + (long long)row * CCH;
  float* orow = out + (long long)row * CCH;
  if (gg == 0) {
    for (int c = threadIdx.x; c < CCH; c += 128) orow[c] = xr[c];
    return;
  }
  int n = b * 1024 + gg - 1;
  int c3 = cluster[n];
  const float* a3 = t3 + (long long)c3 * CCH;
  float nb = fmaxf(t3norm[c3], 1e-8f);
  __shared__ float sb[2];
  float w[NSUP];
  const float* rows[NSUP];
  float tot = 0.f;
  for (int i = 0; i < NSUP; i++) {
    int s = fgi[i * NFEAT + n];
    const float* ar = t1d + ((long long)i * SEG2 + s) * CCH;
    rows[i] = ar;
    float d = 0.f;
    for (int c = threadIdx.x; c < CCH; c += 128) d += ar[c] * a3[c];
    d = block_reduce_sum<128>(d, sb);
    float na = fmaxf(t1dnorm[i * SEG2 + s], 1e-8f);
    float cosv = d / (na * nb);
    w[i] = (cosv + 1.0f) * 0.5f;
    tot += w[i];
  }
  float inv = 1.0f / tot;
  for (int c = threadIdx.x; c < CCH; c += 128) {
    float acc = 0.f;
    #pragma unroll
    for (int i = 0; i < NSUP; i++) acc += w[i] * rows[i][c];
    orow[c] = xr[c] + 0.3f * acc * inv;
  }
}

extern "C" void kernel_launch(void* const* d_in, const int* in_sizes, int n_in,
                              void* d_out, int out_size, void* d_ws, size_t ws_size,
                              hipStream_t stream)
{
  const float* x_in   = (const float*)d_in[0];
  const float* maskp  = (const float*)d_in[1];
  const float* ln1_g  = (const float*)d_in[2];
  const float* ln1_b  = (const float*)d_in[3];
  const float* ln2_g  = (const float*)d_in[4];
  const float* ln2_b  = (const float*)d_in[5];
  const float* w_in   = (const float*)d_in[6];
  const float* b_in   = (const float*)d_in[7];
  const float* w_out  = (const float*)d_in[8];
  const float* b_out  = (const float*)d_in[9];
  const float* w_fc   = (const float*)d_in[10];
  const float* b_fc   = (const float*)d_in[11];
  const float* w_proj = (const float*)d_in[12];
  const float* b_proj = (const float*)d_in[13];
  const float* wa1    = (const float*)d_in[14];
  const float* ba1    = (const float*)d_in[15];
  const float* wa2    = (const float*)d_in[16];
  const float* ba2    = (const float*)d_in[17];
  const float* g3     = (const float*)d_in[18];
  const float* b3     = (const float*)d_in[19];
  const float* g1d    = (const float*)d_in[20];
  const float* b1d    = (const float*)d_in[21];
  const float* gn3    = (const float*)d_in[22];
  const float* bn3    = (const float*)d_in[23];
  const float* w_attn1= (const float*)d_in[24];
  const float* b_attn1= (const float*)d_in[25];
  const int* sorted_idx = (const int*)d_in[26];
  const int* seg_id   = (const int*)d_in[27];
  const int* cluster  = (const int*)d_in[28];
  const int* fgi      = (const int*)d_in[29];
  float* out = (float*)d_out;
  float* ws = (float*)d_ws;

  size_t off = 0;
  auto alloc = [&](size_t n) { size_t o = off; off += (n + 255) & ~(size_t)255; return o; };
  size_t f_h    = alloc((size_t)NTOK * CCH);
  size_t f_qkv  = alloc((size_t)NTOK * 3 * CCH);
  size_t f_S    = alloc((size_t)NHEAD * 1025 * 1025);
  size_t f_o    = alloc((size_t)NTOK * CCH);
  size_t f_x1   = alloc((size_t)NTOK * CCH);
  size_t f_ffn  = alloc((size_t)NTOK * CCH);
  size_t f_t    = alloc((size_t)NTOK * AAD);
  size_t f_x2   = alloc((size_t)NTOK * CCH);
  size_t f_s3   = alloc((size_t)MSEG * CCH);
  size_t f_t3   = alloc((size_t)MSEG * CCH);
  size_t f_t3n  = alloc((size_t)MSEG);
  size_t f_mean = alloc((size_t)CCH);
  size_t f_var  = alloc((size_t)CCH);
  size_t f_ssum = alloc((size_t)SEG2 * CCH);
  size_t f_smax = alloc((size_t)SEG2 * CCH);
  size_t f_scnt = alloc((size_t)SEG2);
  size_t f_t1d  = alloc((size_t)NSUP * SEG2 * CCH);
  size_t f_t1dn = alloc((size_t)NSUP * SEG2);
  size_t f_fc = f_qkv;   // fc (12.6M floats) reuses dead qkv+S region (15.75M)
  size_t f_y  = f_o;     // o dead after out-proj
  size_t f_fx = f_ffn;   // ffn dead after adapter combine

  // 1) ln1
  ln_kernel<<<NTOK, 128, 0, stream>>>(x_in, ws + f_h, ln1_g, ln1_b, 0);
  // 2) qkv = ln1 @ w_in^T + b_in
  gemm_kernel<true><<<dim3(18, (NTOK + 63) / 64, 1), 256, 0, stream>>>(
      ws + f_h, CCH, 0, 1, w_in, CCH, 0, 1, ws + f_qkv, 3 * CCH, 0,
      NTOK, 3 * CCH, CCH, b_in, 0, 1.0f, nullptr, nullptr, 0, 0, nullptr, 0);
  // 3) attention per batch (S in 25MB reused buffer)
  for (int b = 0; b < NB; b++) {
    const float* qb = ws + f_qkv + (size_t)b * 1025 * 3 * CCH;
    gemm_kernel<true><<<dim3(17, 17, NHEAD), 256, 0, stream>>>(
        qb, 3 * CCH, DHEAD, 1, qb + CCH, 3 * CCH, DHEAD, 1,
        ws + f_S, 1025, 1025 * 1025,
        1025, 1025, DHEAD, nullptr, 0, 1.0f, nullptr, nullptr, 0, 0, nullptr, 0);
    softmax_kernel<<<NHEAD * 1025, 256, 0, stream>>>(ws + f_S);
    gemm_kernel<false><<<dim3(1, 17, NHEAD), 256, 0, stream>>>(
        ws + f_S, 1025, 1025 * 1025, 0, qb + 2 * CCH, 3 * CCH, DHEAD, 1,
        ws + f_o + (size_t)b * 1025 * CCH, CCH, DHEAD,
        1025, DHEAD, 1025, nullptr, 0, 1.0f, nullptr, nullptr, 0, 0, nullptr, 0);
  }
  // 4) x1 = x + o @ w_out^T + b_out
  gemm_kernel<true><<<dim3(6, (NTOK + 63) / 64, 1), 256, 0, stream>>>(
      ws + f_o, CCH, 0, 1, w_out, CCH, 0, 1, ws + f_x1, CCH, 0,
      NTOK, CCH, CCH, b_out, 0, 1.0f, nullptr, x_in, CCH, 0, nullptr, 0);
  // 5) ln2
  ln_kernel<<<NTOK, 128, 0, stream>>>(ws + f_x1, ws + f_h, ln2_g, ln2_b, 0);
  // 6) fc = quick_gelu(ln2 @ w_fc^T + b_fc)
  gemm_kernel<true><<<dim3(24, (NTOK + 63) / 64, 1), 256, 0, stream>>>(
      ws + f_h, CCH, 0, 1, w_fc, CCH, 0, 1, ws + f_fc, 4 * CCH, 0,
      NTOK, 4 * CCH, CCH, b_fc, 1, 1.0f, nullptr, nullptr, 0, 0, nullptr, 0);
  // 7) x_ffn = fc @ w_proj^T + b_proj
  gemm_kernel<true><<<dim3(6, (NTOK + 63) / 64, 1), 256, 0, stream>>>(
      ws + f_fc, 4 * CCH, 0, 1, w_proj, 4 * CCH, 0, 1, ws + f_ffn, CCH, 0,
      NTOK, CCH, 4 * CCH, b_proj, 0, 1.0f, nullptr, nullptr, 0, 0, nullptr, 0);
  // 8) t = quick_gelu(x_ffn @ wa1^T + ba1)
  gemm_kernel<true><<<dim3(1, (NTOK + 63) / 64, 1), 256, 0, stream>>>(
      ws + f_ffn, CCH, 0, 1, wa1, CCH, 0, 1, ws + f_t, AAD, 0,
      NTOK, AAD, CCH, ba1, 1, 1.0f, nullptr, nullptr, 0, 0, nullptr, 0);
  // 9) x2 = x1 + x_ffn + 0.5*(t @ wa2^T + ba2)
  gemm_kernel<true><<<dim3(6, (NTOK + 63) / 64, 1), 256, 0, stream>>>(
      ws + f_t, AAD, 0, 1, wa2, AAD, 0, 1, ws + f_x2, CCH, 0,
      NTOK, CCH, AAD, ba2, 0, 0.5f, nullptr, ws + f_x1, CCH, 0, ws + f_ffn, CCH);
  // 10-12) cluster pooling -> BN+gelu table t3
  seg1_kernel<<<MSEG, 128, 0, stream>>>(ws + f_x2, sorted_idx, seg_id, ws + f_s3);
  bnstats_kernel<<<CCH, 256, 0, stream>>>(ws + f_s3, MSEG, ws + f_mean, ws + f_var);
  bnapply_kernel<<<MSEG, 128, 0, stream>>>(ws + f_s3, ws + f_mean, ws + f_var,
                                           g3, b3, ws + f_t3, ws + f_t3n);
  // 13) six support branches
  for (int i = 0; i < NSUP; i++) {
    ln_kernel<<<NFEAT, 128, 0, stream>>>(ws + f_x2, ws + f_y,
                                         gn3 + i * CCH, bn3 + i * CCH, 1);
    gemm_kernel<true><<<dim3(6, NFEAT / 64, 1), 256, 0, stream>>>(
        ws + f_y, CCH, 0, 1, w_attn1 + (size_t)i * CCH * CCH, CCH, 0, 1,
        ws + f_fx, CCH, 0,
        NFEAT, CCH, CCH, b_attn1 + i * CCH, 0, 1.0f, maskp + (size_t)i * NFEAT,
        ws + f_x2, CCH, 1, nullptr, 0);
    seginit_kernel<<<(SEG2 * CCH + 255) / 256, 256, 0, stream>>>(
        ws + f_ssum, ws + f_smax, ws + f_scnt);
    scatter_kernel<<<NFEAT, 128, 0, stream>>>(ws + f_fx, fgi + (size_t)i * NFEAT,
                                              ws + f_ssum, ws + f_smax, ws + f_scnt);
    segcombine_kernel<<<(SEG2 * CCH + 255) / 256, 256, 0, stream>>>(
        ws + f_ssum, ws + f_smax, ws + f_scnt);
    bnstats_kernel<<<CCH, 256, 0, stream>>>(ws + f_ssum, SEG2, ws + f_mean, ws + f_var);
    bnapply_kernel<<<SEG2, 128, 0, stream>>>(ws + f_ssum, ws + f_mean, ws + f_var,
        g1d + i * CCH, b1d + i * CCH,
        ws + f_t1d + (size_t)i * SEG2 * CCH, ws + f_t1dn + (size_t)i * SEG2);
  }
  // 14) cosine weighting + output
  final_kernel<<<NTOK, 128, 0, stream>>>(ws + f_x2, ws + f_t3, ws + f_t3n,
      ws + f_t1d, ws + f_t1dn, cluster, fgi, out);
}

// Round 2
// 2020.459 us; speedup vs baseline: 1.2360x; 1.2360x over previous
//
#include <hip/hip_runtime.h>
#include <hip/hip_bf16.h>
#include <float.h>
#include <math.h>

#define NB 8
#define CCH 384
#define NHEAD 6
#define DHEAD 64
#define AAD 48
#define MSEG 1024
#define NSUP 6
#define NTOK 8200
#define NFEAT 8192
#define SEG2 1536
#define SEQ 1025
#define SEQP 1088   // padded seq for PV K-dim (multiple of 64)

typedef __hip_bfloat16 bf16;
typedef __attribute__((ext_vector_type(8))) short short8;
typedef __attribute__((ext_vector_type(4))) float floatx4;

// feat row n (0..8191) -> row index in (B,1025,C) token array, skipping CLS
static __device__ __forceinline__ long long tokrow(int n) {
  return (long long)n + (n >> 10) + 1;
}

template<int NT>
static __device__ __forceinline__ float block_reduce_sum(float v, float* s) {
  #pragma unroll
  for (int off = 32; off > 0; off >>= 1) v += __shfl_down(v, off, 64);
  int lane = threadIdx.x & 63, wid = threadIdx.x >> 6;
  if (lane == 0) s[wid] = v;
  __syncthreads();
  if (threadIdx.x == 0) {
    float t = s[0];
    #pragma unroll
    for (int w = 1; w < NT / 64; w++) t += s[w];
    s[0] = t;
  }
  __syncthreads();
  float r = s[0];
  __syncthreads();
  return r;
}

template<int NT>
static __device__ __forceinline__ float block_reduce_max(float v, float* s) {
  #pragma unroll
  for (int off = 32; off > 0; off >>= 1) v = fmaxf(v, __shfl_down(v, off, 64));
  int lane = threadIdx.x & 63, wid = threadIdx.x >> 6;
  if (lane == 0) s[wid] = v;
  __syncthreads();
  if (threadIdx.x == 0) {
    float t = s[0];
    #pragma unroll
    for (int w = 1; w < NT / 64; w++) t = fmaxf(t, s[w]);
    s[0] = t;
  }
  __syncthreads();
  float r = s[0];
  __syncthreads();
  return r;
}

static __device__ __forceinline__ void atomicMaxFloat(float* addr, float val) {
  if (val >= 0.f) atomicMax((int*)addr, __float_as_int(val));
  else            atomicMin((unsigned int*)addr, __float_as_uint(val));
}

// ---------------------------------------------------------------------------
// MFMA bf16 GEMM:  C[m,n] = sum_k A[m,k] * Bt[n,k]   (Bt = B stored N x K)
// Block = 256 threads = 4 waves; wave tile 64x64 via 16x16x32 bf16 MFMA.
// WM x WN waves -> BM = WM*64, BN = WN*64.  BK = 64.
// LDS layout: 16B granules indexed (k8, row) with +2 row padding -> 2-way max.
// Epilogue: v = act(acc + bias[n]) * scale * rowmask[m] + res1 + res2,
//           optional fp32 and/or bf16 stores.  K must be a multiple of 8.
// ---------------------------------------------------------------------------
template<int WM, int WN>
__global__ __launch_bounds__(256) void mgemm_kernel(
    const bf16* __restrict__ A, int lda, long long sAh,
    const bf16* __restrict__ B, int ldb, long long sBh,
    float* __restrict__ outF, int ldcF, long long sCFh,
    bf16* __restrict__ outB, int ldcB, long long sCBh,
    int M, int N, int K,
    const float* __restrict__ bias, int act, float scale,
    const float* __restrict__ rowmask,
    const float* __restrict__ res1, int ldr1, int res1skip,
    const float* __restrict__ res2, int ldr2)
{
  constexpr int BM = WM * 64, BN = WN * 64;
  constexpr int APAD = BM + 2, BPAD = BN + 2;
  __shared__ uint4 Asg[8 * APAD];
  __shared__ uint4 Bsg[8 * BPAD];
  const bf16* Ap = A + (long long)blockIdx.z * sAh;
  const bf16* Bp = B + (long long)blockIdx.z * sBh;
  const int tid = threadIdx.x;
  const int m0 = blockIdx.y * BM, n0 = blockIdx.x * BN;
  const int lane = tid & 63, wid = tid >> 6;
  const int wm = (wid % WM) * 64, wn = (wid / WM) * 64;
  const int q = lane >> 4, ln = lane & 15;

  uint4 areg[2 * WM], breg[2 * WN];
  const uint4 zero4 = make_uint4(0, 0, 0, 0);

  auto loadTiles = [&](int k0) {
    #pragma unroll
    for (int p = 0; p < 2 * WM; p++) {
      int idx = p * 256 + tid;
      int k8 = idx & 7, m = idx >> 3;
      int gm = m0 + m, gk = k0 + k8 * 8;
      areg[p] = (gm < M && gk < K)
          ? *reinterpret_cast<const uint4*>(Ap + (long long)gm * lda + gk) : zero4;
    }
    #pragma unroll
    for (int p = 0; p < 2 * WN; p++) {
      int idx = p * 256 + tid;
      int k8 = idx & 7, n = idx >> 3;
      int gn = n0 + n, gk = k0 + k8 * 8;
      breg[p] = (gn < N && gk < K)
          ? *reinterpret_cast<const uint4*>(Bp + (long long)gn * ldb + gk) : zero4;
    }
  };
  auto storeTiles = [&]() {
    #pragma unroll
    for (int p = 0; p < 2 * WM; p++) {
      int idx = p * 256 + tid;
      int k8 = idx & 7, m = idx >> 3;
      Asg[k8 * APAD + m] = areg[p];
    }
    #pragma unroll
    for (int p = 0; p < 2 * WN; p++) {
      int idx = p * 256 + tid;
      int k8 = idx & 7, n = idx >> 3;
      Bsg[k8 * BPAD + n] = breg[p];
    }
  };

  floatx4 acc[4][4];
  #pragma unroll
  for (int i = 0; i < 4; i++)
    #pragma unroll
    for (int j = 0; j < 4; j++) acc[i][j] = (floatx4){0.f, 0.f, 0.f, 0.f};

  const int nk = (K + 63) >> 6;
  loadTiles(0);
  for (int t = 0; t < nk; t++) {
    __syncthreads();
    storeTiles();
    __syncthreads();
    if (t + 1 < nk) loadTiles((t + 1) * 64);
    #pragma unroll
    for (int ks = 0; ks < 2; ks++) {
      short8 af[4], bfr[4];
      #pragma unroll
      for (int i = 0; i < 4; i++)
        af[i] = *reinterpret_cast<const short8*>(&Asg[(ks * 4 + q) * APAD + wm + i * 16 + ln]);
      #pragma unroll
      for (int j = 0; j < 4; j++)
        bfr[j] = *reinterpret_cast<const short8*>(&Bsg[(ks * 4 + q) * BPAD + wn + j * 16 + ln]);
      #pragma unroll
      for (int i = 0; i < 4; i++)
        #pragma unroll
        for (int j = 0; j < 4; j++)
          acc[i][j] = __builtin_amdgcn_mfma_f32_16x16x32_bf16(af[i], bfr[j], acc[i][j], 0, 0, 0);
    }
  }

  float* cF = outF ? outF + (long long)blockIdx.z * sCFh : nullptr;
  bf16*  cB = outB ? outB + (long long)blockIdx.z * sCBh : nullptr;
  #pragma unroll
  for (int i = 0; i < 4; i++) {
    #pragma unroll
    for (int r = 0; r < 4; r++) {
      int gm = m0 + wm + i * 16 + q * 4 + r;
      if (gm >= M) continue;
      float rm = rowmask ? rowmask[gm] : 1.0f;
      long long r1off = 0;
      if (res1) r1off = (res1skip ? tokrow(gm) : (long long)gm) * ldr1;
      #pragma unroll
      for (int j = 0; j < 4; j++) {
        int gn = n0 + wn + j * 16 + ln;
        if (gn >= N) continue;
        float v = acc[i][j][r];
        if (bias) v += bias[gn];
        if (act) v = v / (1.0f + __expf(-1.702f * v));  // quick_gelu
        v *= scale * rm;
        if (res1) v += res1[r1off + gn];
        if (res2) v += res2[(long long)gm * ldr2 + gn];
        if (cF) cF[(long long)gm * ldcF + gn] = v;
        if (cB) cB[(long long)gm * ldcB + gn] = __float2bfloat16(v);
      }
    }
  }
}

// fp32 -> bf16 convert (n % 4 == 0)
__global__ void tobf16_kernel(const float* __restrict__ s, bf16* __restrict__ d, int n)
{
  int i = (blockIdx.x * 256 + threadIdx.x) * 4;
  if (i >= n) return;
  float4 v = *reinterpret_cast<const float4*>(s + i);
  d[i]     = __float2bfloat16(v.x);
  d[i + 1] = __float2bfloat16(v.y);
  d[i + 2] = __float2bfloat16(v.z);
  d[i + 3] = __float2bfloat16(v.w);
}

// LayerNorm over C=384, bf16 output; skipcls remaps to non-CLS token rows
__global__ __launch_bounds__(128) void ln_kernel(
    const float* __restrict__ in, bf16* __restrict__ out,
    const float* __restrict__ g, const float* __restrict__ b, int skipcls)
{
  int r = blockIdx.x;
  long long ir = skipcls ? tokrow(r) : (long long)r;
  const float* x = in + ir * CCH;
  __shared__ float sb[2];
  int c = threadIdx.x;
  float v0 = x[c], v1 = x[c + 128], v2 = x[c + 256];
  float s  = block_reduce_sum<128>(v0 + v1 + v2, sb);
  float s2 = block_reduce_sum<128>(v0 * v0 + v1 * v1 + v2 * v2, sb);
  float m = s * (1.0f / CCH);
  float var = s2 * (1.0f / CCH) - m * m;
  float rstd = rsqrtf(var + 1e-5f);
  bf16* o = out + (long long)r * CCH;
  o[c]       = __float2bfloat16((v0 - m) * rstd * g[c]       + b[c]);
  o[c + 128] = __float2bfloat16((v1 - m) * rstd * g[c + 128] + b[c + 128]);
  o[c + 256] = __float2bfloat16((v2 - m) * rstd * g[c + 256] + b[c + 256]);
}

// softmax over rows of length 1025 (logits pre-scaled); bf16 out, ld 1088 zero-pad
__global__ __launch_bounds__(256) void softmax_kernel(
    const float* __restrict__ S, bf16* __restrict__ P)
{
  long long r = blockIdx.x;
  const float* p = S + r * SEQ;
  bf16* o = P + r * SEQP;
  int tid = threadIdx.x;
  float vals[5];
  float lm = -FLT_MAX;
  #pragma unroll
  for (int e = 0; e < 5; e++) {
    int c = tid + e * 256;
    vals[e] = (c < SEQ) ? p[c] : -FLT_MAX;
    lm = fmaxf(lm, vals[e]);
  }
  __shared__ float sb[4];
  float m = block_reduce_max<256>(lm, sb);
  float ls = 0.f;
  #pragma unroll
  for (int e = 0; e < 5; e++) {
    int c = tid + e * 256;
    if (c < SEQ) { vals[e] = __expf(vals[e] - m); ls += vals[e]; }
  }
  float s = block_reduce_sum<256>(ls, sb);
  float inv = 1.0f / s;
  #pragma unroll
  for (int e = 0; e < 5; e++) {
    int c = tid + e * 256;
    if (c < SEQ) o[c] = __float2bfloat16(vals[e] * inv);
  }
  if (tid < SEQP - SEQ) o[SEQ + tid] = __float2bfloat16(0.f);
}

// V (within qkv, [s][h*64+d]) -> Vt [bh][d][s padded to 1088], zero-filled tail
__global__ __launch_bounds__(256) void vtrans_kernel(
    const bf16* __restrict__ qkv, bf16* __restrict__ Vt)
{
  __shared__ bf16 tile[64][68];
  int bh = blockIdx.y;
  int b = bh / NHEAD, h = bh % NHEAD;
  int s0 = blockIdx.x * 64;
  int dq = (threadIdx.x & 15) * 4;
  int sl = threadIdx.x >> 4;
  #pragma unroll
  for (int p = 0; p < 4; p++) {
    int sloc = sl + p * 16;
    int s = s0 + sloc;
    uint2 v = make_uint2(0, 0);
    if (s < SEQ)
      v = *reinterpret_cast<const uint2*>(
            qkv + ((long long)(b * SEQ + s)) * (3 * CCH) + 2 * CCH + h * DHEAD + dq);
    *reinterpret_cast<uint2*>(&tile[sloc][dq]) = v;
  }
  __syncthreads();
  #pragma unroll
  for (int p = 0; p < 4; p++) {
    int dloc = sl + p * 16;
    int s4 = dq;
    bf16 t0 = tile[s4 + 0][dloc], t1 = tile[s4 + 1][dloc];
    bf16 t2 = tile[s4 + 2][dloc], t3 = tile[s4 + 3][dloc];
    bf16* dst = Vt + ((long long)bh * DHEAD + dloc) * SEQP + s0 + s4;
    dst[0] = t0; dst[1] = t1; dst[2] = t2; dst[3] = t3;
  }
}

// sorted-segment max+mean over cluster ids; one block per segment
__global__ __launch_bounds__(128) void seg1_kernel(
    const float* __restrict__ x2, const int* __restrict__ sorted_idx,
    const int* __restrict__ seg_id, float* __restrict__ s3)
{
  int s = blockIdx.x;
  int lo = 0, hi = NFEAT;
  while (lo < hi) { int mid = (lo + hi) >> 1; if (seg_id[mid] < s) lo = mid + 1; else hi = mid; }
  int start = lo;
  hi = NFEAT;
  while (lo < hi) { int mid = (lo + hi) >> 1; if (seg_id[mid] < s + 1) lo = mid + 1; else hi = mid; }
  int end = lo;
  int cnt = end - start;
  for (int c = threadIdx.x; c < CCH; c += 128) {
    float sum = 0.f, mx = -FLT_MAX;
    for (int r = start; r < end; r++) {
      int n = sorted_idx[r];
      float v = x2[tokrow(n) * CCH + c];
      sum += v; mx = fmaxf(mx, v);
    }
    float u = (cnt > 0 ? mx : 0.f) + sum / fmaxf((float)cnt, 1.0f);
    s3[(long long)s * CCH + c] = u;
  }
}

// per-channel batchnorm stats over `rows` rows
__global__ __launch_bounds__(256) void bnstats_kernel(
    const float* __restrict__ u, int rows,
    float* __restrict__ mean, float* __restrict__ var)
{
  int c = blockIdx.x;
  float s = 0.f, s2 = 0.f;
  for (int r = threadIdx.x; r < rows; r += 256) {
    float v = u[(long long)r * CCH + c];
    s += v; s2 += v * v;
  }
  __shared__ float sb[4];
  s  = block_reduce_sum<256>(s, sb);
  s2 = block_reduce_sum<256>(s2, sb);
  if (threadIdx.x == 0) {
    float m = s / rows;
    mean[c] = m;
    var[c] = s2 / rows - m * m;
  }
}

// apply BN + exact gelu, store result and row L2 norm; one block per row
__global__ __launch_bounds__(128) void bnapply_kernel(
    const float* __restrict__ u,
    const float* __restrict__ mean, const float* __restrict__ var,
    const float* __restrict__ g, const float* __restrict__ b,
    float* __restrict__ t, float* __restrict__ norms)
{
  int r = blockIdx.x;
  float ss = 0.f;
  #pragma unroll
  for (int e = 0; e < 3; e++) {
    int c = threadIdx.x + e * 128;
    float v = u[(long long)r * CCH + c];
    float y = (v - mean[c]) * rsqrtf(var[c] + 1e-5f) * g[c] + b[c];
    float ge = 0.5f * y * (1.0f + erff(y * 0.70710678118654752f));
    t[(long long)r * CCH + c] = ge;
    ss += ge * ge;
  }
  __shared__ float sb[2];
  ss = block_reduce_sum<128>(ss, sb);
  if (threadIdx.x == 0) norms[r] = sqrtf(ss);
}

__global__ void seginit_kernel(float* sum, float* mx, float* cnt)
{
  int idx = blockIdx.x * 256 + threadIdx.x;
  if (idx < SEG2 * CCH) { sum[idx] = 0.f; mx[idx] = -FLT_MAX; }
  if (idx < SEG2) cnt[idx] = 0.f;
}

__global__ __launch_bounds__(128) void scatter_kernel(
    const float* __restrict__ fx, const int* __restrict__ fgi,
    float* __restrict__ sum, float* __restrict__ mx, float* __restrict__ cnt)
{
  int n = blockIdx.x;
  int s = fgi[n];
  const float* row = fx + (long long)n * CCH;
  float* ps = sum + (long long)s * CCH;
  float* pm = mx + (long long)s * CCH;
  for (int c = threadIdx.x; c < CCH; c += 128) {
    float v = row[c];
    atomicAdd(ps + c, v);
    atomicMaxFloat(pm + c, v);
  }
  if (threadIdx.x == 0) atomicAdd(cnt + s, 1.0f);
}

__global__ void segcombine_kernel(float* __restrict__ sum,
                                  const float* __restrict__ mx,
                                  const float* __restrict__ cnt)
{
  int idx = blockIdx.x * 256 + threadIdx.x;
  if (idx >= SEG2 * CCH) return;
  int r = idx / CCH;
  float c = cnt[r];
  float m = (c > 0.f) ? mx[idx] : 0.f;
  sum[idx] = m + sum[idx] / fmaxf(c, 1.0f);
}

// cosine-sim weighting + final output (handles CLS copy too)
__global__ __launch_bounds__(128) void final_kernel(
    const float* __restrict__ x2, const float* __restrict__ t3,
    const float* __restrict__ t3norm, const float* __restrict__ t1d,
    const float* __restrict__ t1dnorm, const int* __restrict__ cluster,
    const int* __restrict__ fgi, float* __restrict__ out)
{
  int row = blockIdx.x;
  int b = row / SEQ, gg = row - b * SEQ;
  const float* xr = x2 + (long long)row * CCH;
  float* orow = out + (long long)row * CCH;
  if (gg == 0) {
    for (int c = threadIdx.x; c < CCH; c += 128) orow[c] = xr[c];
    return;
  }
  int n = b * 1024 + gg - 1;
  int c3 = cluster[n];
  const float* a3 = t3 + (long long)c3 * CCH;
  float nb = fmaxf(t3norm[c3], 1e-8f);
  __shared__ float sb[2];
  float w[NSUP];
  const float* rows[NSUP];
  float tot = 0.f;
  for (int i = 0; i < NSUP; i++) {
    int s = fgi[i * NFEAT + n];
    const float* ar = t1d + ((long long)i * SEG2 + s) * CCH;
    rows[i] = ar;
    float d = 0.f;
    for (int c = threadIdx.x; c < CCH; c += 128) d += ar[c] * a3[c];
    d = block_reduce_sum<128>(d, sb);
    float na = fmaxf(t1dnorm[i * SEG2 + s], 1e-8f);
    float cosv = d / (na * nb);
    w[i] = (cosv + 1.0f) * 0.5f;
    tot += w[i];
  }
  float inv = 1.0f / tot;
  for (int c = threadIdx.x; c < CCH; c += 128) {
    float acc = 0.f;
    #pragma unroll
    for (int i = 0; i < NSUP; i++) acc += w[i] * rows[i][c];
    orow[c] = xr[c] + 0.3f * acc * inv;
  }
}

extern "C" void kernel_launch(void* const* d_in, const int* in_sizes, int n_in,
                              void* d_out, int out_size, void* d_ws, size_t ws_size,
                              hipStream_t stream)
{
  const float* x_in   = (const float*)d_in[0];
  const float* maskp  = (const float*)d_in[1];
  const float* ln1_g  = (const float*)d_in[2];
  const float* ln1_b  = (const float*)d_in[3];
  const float* ln2_g  = (const float*)d_in[4];
  const float* ln2_b  = (const float*)d_in[5];
  const float* w_in   = (const float*)d_in[6];
  const float* b_in   = (const float*)d_in[7];
  const float* w_out  = (const float*)d_in[8];
  const float* b_out  = (const float*)d_in[9];
  const float* w_fc   = (const float*)d_in[10];
  const float* b_fc   = (const float*)d_in[11];
  const float* w_proj = (const float*)d_in[12];
  const float* b_proj = (const float*)d_in[13];
  const float* wa1    = (const float*)d_in[14];
  const float* ba1    = (const float*)d_in[15];
  const float* wa2    = (const float*)d_in[16];
  const float* ba2    = (const float*)d_in[17];
  const float* g3     = (const float*)d_in[18];
  const float* b3     = (const float*)d_in[19];
  const float* g1d    = (const float*)d_in[20];
  const float* b1d    = (const float*)d_in[21];
  const float* gn3    = (const float*)d_in[22];
  const float* bn3    = (const float*)d_in[23];
  const float* w_attn1= (const float*)d_in[24];
  const float* b_attn1= (const float*)d_in[25];
  const int* sorted_idx = (const int*)d_in[26];
  const int* seg_id   = (const int*)d_in[27];
  const int* cluster  = (const int*)d_in[28];
  const int* fgi      = (const int*)d_in[29];
  float* out = (float*)d_out;
  char* wsb = (char*)d_ws;

  size_t off = 0;
  auto alloc = [&](size_t bytes) { size_t o = off; off += (bytes + 255) & ~(size_t)255; return o; };
  size_t o_hbf  = alloc((size_t)NTOK * CCH * 2);          // ln out (bf16); reused as y_bf
  size_t o_qkv  = alloc((size_t)NTOK * 3 * CCH * 2);      // qkv bf16; reused as ffn fp32
  size_t o_S    = alloc((size_t)NHEAD * SEQ * SEQ * 4);   // scores fp32 (per-batch); reused as fc_bf
  size_t o_P    = alloc((size_t)NHEAD * SEQ * SEQP * 2);  // probs bf16 (per-batch); reused as fx fp32
  size_t o_Vt   = alloc((size_t)NB * NHEAD * DHEAD * SEQP * 2); // V^T bf16; reused as t_bf
  size_t o_obf  = alloc((size_t)NTOK * CCH * 2);          // attn out bf16; reused as ffn_bf
  size_t o_x1   = alloc((size_t)NTOK * CCH * 4);
  size_t o_x2   = alloc((size_t)NTOK * CCH * 4);
  size_t o_s3   = alloc((size_t)MSEG * CCH * 4);
  size_t o_t3   = alloc((size_t)MSEG * CCH * 4);
  size_t o_t3n  = alloc((size_t)MSEG * 4);
  size_t o_mean = alloc((size_t)CCH * 4);
  size_t o_var  = alloc((size_t)CCH * 4);
  size_t o_ssum = alloc((size_t)SEG2 * CCH * 4);
  size_t o_smax = alloc((size_t)SEG2 * CCH * 4);
  size_t o_scnt = alloc((size_t)SEG2 * 4);
  size_t o_t1d  = alloc((size_t)NSUP * SEG2 * CCH * 4);
  size_t o_t1dn = alloc((size_t)NSUP * SEG2 * 4);
  size_t o_wib  = alloc((size_t)3 * CCH * CCH * 2);
  size_t o_wob  = alloc((size_t)CCH * CCH * 2);
  size_t o_wfb  = alloc((size_t)4 * CCH * CCH * 2);
  size_t o_wpb  = alloc((size_t)CCH * 4 * CCH * 2);
  size_t o_wa1b = alloc((size_t)AAD * CCH * 2);
  size_t o_wa2b = alloc((size_t)CCH * AAD * 2);
  size_t o_watb = alloc((size_t)NSUP * CCH * CCH * 2);

  bf16*  h_bf   = (bf16*)(wsb + o_hbf);
  bf16*  qkv_bf = (bf16*)(wsb + o_qkv);
  float* Sbuf   = (float*)(wsb + o_S);
  bf16*  Pbuf   = (bf16*)(wsb + o_P);
  bf16*  Vt     = (bf16*)(wsb + o_Vt);
  bf16*  o_bf   = (bf16*)(wsb + o_obf);
  float* x1     = (float*)(wsb + o_x1);
  float* x2     = (float*)(wsb + o_x2);
  float* s3     = (float*)(wsb + o_s3);
  float* t3     = (float*)(wsb + o_t3);
  float* t3n    = (float*)(wsb + o_t3n);
  float* meanb  = (float*)(wsb + o_mean);
  float* varb   = (float*)(wsb + o_var);
  float* ssum   = (float*)(wsb + o_ssum);
  float* smax   = (float*)(wsb + o_smax);
  float* scnt   = (float*)(wsb + o_scnt);
  float* t1d    = (float*)(wsb + o_t1d);
  float* t1dn   = (float*)(wsb + o_t1dn);
  bf16*  w_in_b = (bf16*)(wsb + o_wib);
  bf16*  w_out_b= (bf16*)(wsb + o_wob);
  bf16*  w_fc_b = (bf16*)(wsb + o_wfb);
  bf16*  w_pj_b = (bf16*)(wsb + o_wpb);
  bf16*  wa1_b  = (bf16*)(wsb + o_wa1b);
  bf16*  wa2_b  = (bf16*)(wsb + o_wa2b);
  bf16*  wat_b  = (bf16*)(wsb + o_watb);
  // region reuse (all safe by liveness ordering)
  bf16*  fc_bf  = (bf16*)(wsb + o_S);
  float* ffn    = (float*)(wsb + o_qkv);
  bf16*  ffn_bf = (bf16*)(wsb + o_obf);
  bf16*  t_bf   = (bf16*)(wsb + o_Vt);
  bf16*  y_bf   = (bf16*)(wsb + o_hbf);
  float* fx     = (float*)(wsb + o_P);

  auto cvt = [&](const float* s, bf16* d, int n) {
    tobf16_kernel<<<(n / 4 + 255) / 256, 256, 0, stream>>>(s, d, n);
  };
  cvt(w_in,    w_in_b, 3 * CCH * CCH);
  cvt(w_out,   w_out_b, CCH * CCH);
  cvt(w_fc,    w_fc_b, 4 * CCH * CCH);
  cvt(w_proj,  w_pj_b, CCH * 4 * CCH);
  cvt(wa1,     wa1_b, AAD * CCH);
  cvt(wa2,     wa2_b, CCH * AAD);
  cvt(w_attn1, wat_b, NSUP * CCH * CCH);

  // 1) ln1 -> h_bf
  ln_kernel<<<NTOK, 128, 0, stream>>>(x_in, h_bf, ln1_g, ln1_b, 0);
  // 2) qkv = ln1 @ w_in^T + b_in  (bf16 out)
  mgemm_kernel<2, 2><<<dim3(9, 65, 1), 256, 0, stream>>>(
      h_bf, CCH, 0, w_in_b, CCH, 0,
      nullptr, 0, 0, qkv_bf, 3 * CCH, 0,
      NTOK, 3 * CCH, CCH, b_in, 0, 1.0f, nullptr, nullptr, 0, 0, nullptr, 0);
  // 3) V transpose (all batches)
  vtrans_kernel<<<dim3(SEQP / 64, NB * NHEAD), 256, 0, stream>>>(qkv_bf, Vt);
  // 4) attention per batch
  for (int b = 0; b < NB; b++) {
    const bf16* qb = qkv_bf + (size_t)b * SEQ * 3 * CCH;
    mgemm_kernel<2, 2><<<dim3(9, 9, NHEAD), 256, 0, stream>>>(
        qb, 3 * CCH, DHEAD, qb + CCH, 3 * CCH, DHEAD,
        Sbuf, SEQ, (long long)SEQ * SEQ, nullptr, 0, 0,
        SEQ, SEQ, DHEAD, nullptr, 0, 0.125f, nullptr, nullptr, 0, 0, nullptr, 0);
    softmax_kernel<<<NHEAD * SEQ, 256, 0, stream>>>(Sbuf, Pbuf);
    mgemm_kernel<4, 1><<<dim3(1, 5, NHEAD), 256, 0, stream>>>(
        Pbuf, SEQP, (long long)SEQ * SEQP,
        Vt + (size_t)b * NHEAD * DHEAD * SEQP, SEQP, (long long)DHEAD * SEQP,
        nullptr, 0, 0, o_bf + (size_t)b * SEQ * CCH, CCH, DHEAD,
        SEQ, DHEAD, SEQP, nullptr, 0, 1.0f, nullptr, nullptr, 0, 0, nullptr, 0);
  }
  // 5) x1 = x + o @ w_out^T + b_out
  mgemm_kernel<2, 2><<<dim3(3, 65, 1), 256, 0, stream>>>(
      o_bf, CCH, 0, w_out_b, CCH, 0,
      x1, CCH, 0, nullptr, 0, 0,
      NTOK, CCH, CCH, b_out, 0, 1.0f, nullptr, x_in, CCH, 0, nullptr, 0);
  // 6) ln2 -> h_bf
  ln_kernel<<<NTOK, 128, 0, stream>>>(x1, h_bf, ln2_g, ln2_b, 0);
  // 7) fc = quick_gelu(ln2 @ w_fc^T + b_fc)  (bf16)
  mgemm_kernel<2, 2><<<dim3(12, 65, 1), 256, 0, stream>>>(
      h_bf, CCH, 0, w_fc_b, CCH, 0,
      nullptr, 0, 0, fc_bf, 4 * CCH, 0,
      NTOK, 4 * CCH, CCH, b_fc, 1, 1.0f, nullptr, nullptr, 0, 0, nullptr, 0);
  // 8) x_ffn = fc @ w_proj^T + b_proj  (fp32 + bf16)
  mgemm_kernel<2, 2><<<dim3(3, 65, 1), 256, 0, stream>>>(
      fc_bf, 4 * CCH, 0, w_pj_b, 4 * CCH, 0,
      ffn, CCH, 0, ffn_bf, CCH, 0,
      NTOK, CCH, 4 * CCH, b_proj, 0, 1.0f, nullptr, nullptr, 0, 0, nullptr, 0);
  // 9) t = quick_gelu(x_ffn @ wa1^T + ba1)  (bf16)
  mgemm_kernel<4, 1><<<dim3(1, 33, 1), 256, 0, stream>>>(
      ffn_bf, CCH, 0, wa1_b, CCH, 0,
      nullptr, 0, 0, t_bf, AAD, 0,
      NTOK, AAD, CCH, ba1, 1, 1.0f, nullptr, nullptr, 0, 0, nullptr, 0);
  // 10) x2 = x1 + x_ffn + 0.5*(t @ wa2^T + ba2)
  mgemm_kernel<2, 2><<<dim3(3, 65, 1), 256, 0, stream>>>(
      t_bf, AAD, 0, wa2_b, AAD, 0,
      x2, CCH, 0, nullptr, 0, 0,
      NTOK, CCH, AAD, ba2, 0, 0.5f, nullptr, x1, CCH, 0, ffn, CCH);
  // 11) cluster pooling -> BN+gelu table t3
  seg1_kernel<<<MSEG, 128, 0, stream>>>(x2, sorted_idx, seg_id, s3);
  bnstats_kernel<<<CCH, 256, 0, stream>>>(s3, MSEG, meanb, varb);
  bnapply_kernel<<<MSEG, 128, 0, stream>>>(s3, meanb, varb, g3, b3, t3, t3n);
  // 12) six support branches
  for (int i = 0; i < NSUP; i++) {
    ln_kernel<<<NFEAT, 128, 0, stream>>>(x2, y_bf, gn3 + i * CCH, bn3 + i * CCH, 1);
    mgemm_kernel<2, 2><<<dim3(3, 64, 1), 256, 0, stream>>>(
        y_bf, CCH, 0, wat_b + (size_t)i * CCH * CCH, CCH, 0,
        fx, CCH, 0, nullptr, 0, 0,
        NFEAT, CCH, CCH, b_attn1 + i * CCH, 0, 1.0f, maskp + (size_t)i * NFEAT,
        x2, CCH, 1, nullptr, 0);
    seginit_kernel<<<(SEG2 * CCH + 255) / 256, 256, 0, stream>>>(ssum, smax, scnt);
    scatter_kernel<<<NFEAT, 128, 0, stream>>>(fx, fgi + (size_t)i * NFEAT, ssum, smax, scnt);
    segcombine_kernel<<<(SEG2 * CCH + 255) / 256, 256, 0, stream>>>(ssum, smax, scnt);
    bnstats_kernel<<<CCH, 256, 0, stream>>>(ssum, SEG2, meanb, varb);
    bnapply_kernel<<<SEG2, 128, 0, stream>>>(ssum, meanb, varb,
        g1d + i * CCH, b1d + i * CCH,
        t1d + (size_t)i * SEG2 * CCH, t1dn + (size_t)i * SEG2);
  }
  // 13) cosine weighting + output
  final_kernel<<<NTOK, 128, 0, stream>>>(x2, t3, t3n, t1d, t1dn, cluster, fgi, out);
}

// Round 3
// 1054.860 us; speedup vs baseline: 2.3674x; 1.9154x over previous
//
#include <hip/hip_runtime.h>
#include <hip/hip_bf16.h>
#include <float.h>
#include <math.h>

#define NB 8
#define CCH 384
#define NHEAD 6
#define DHEAD 64
#define AAD 48
#define MSEG 1024
#define NSUP 6
#define NTOK 8200
#define NFEAT 8192
#define SEG2 1536
#define SEQ 1025
#define SEQP 1088   // padded seq (multiple of 64)

typedef __hip_bfloat16 bf16;
typedef __attribute__((ext_vector_type(8))) short short8;
typedef __attribute__((ext_vector_type(4))) float floatx4;

// feat row n (0..8191) -> row index in (B,1025,C) token array, skipping CLS
static __device__ __forceinline__ long long tokrow(int n) {
  return (long long)n + (n >> 10) + 1;
}

template<int NT>
static __device__ __forceinline__ float block_reduce_sum(float v, float* s) {
  #pragma unroll
  for (int off = 32; off > 0; off >>= 1) v += __shfl_down(v, off, 64);
  int lane = threadIdx.x & 63, wid = threadIdx.x >> 6;
  if (lane == 0) s[wid] = v;
  __syncthreads();
  if (threadIdx.x == 0) {
    float t = s[0];
    #pragma unroll
    for (int w = 1; w < NT / 64; w++) t += s[w];
    s[0] = t;
  }
  __syncthreads();
  float r = s[0];
  __syncthreads();
  return r;
}

static __device__ __forceinline__ void atomicMaxFloat(float* addr, float val) {
  if (val >= 0.f) atomicMax((int*)addr, __float_as_int(val));
  else            atomicMin((unsigned int*)addr, __float_as_uint(val));
}

// ---------------------------------------------------------------------------
// MFMA bf16 GEMM:  C[m,n] = sum_k A[m,k] * Bt[n,k]   (Bt stored N x K)
// 4 waves, wave tile 64x64 via 16x16x32 bf16 MFMA. BK=64. K % 8 == 0.
// Epilogue: v = act(acc + bias[z][n]) * scale * rowmask[z][m] + res1 + res2.
// Output: fp32 and/or bf16 stores, or atomic segment-scatter (sum+max).
// ---------------------------------------------------------------------------
template<int WM, int WN>
__global__ __launch_bounds__(256) void mgemm_kernel(
    const bf16* __restrict__ A, int lda, long long sAh,
    const bf16* __restrict__ B, int ldb, long long sBh,
    float* __restrict__ outF, int ldcF, long long sCFh,
    bf16* __restrict__ outB, int ldcB, long long sCBh,
    int M, int N, int K,
    const float* __restrict__ bias, int act, float scale,
    const float* __restrict__ rowmask,
    const float* __restrict__ res1, int ldr1, int res1skip,
    const float* __restrict__ res2, int ldr2,
    long long sBias, long long sMask,
    const int* __restrict__ segidx, long long sSeg,
    float* __restrict__ scatSum, float* __restrict__ scatMax, long long sScat)
{
  constexpr int BM = WM * 64, BN = WN * 64;
  constexpr int APAD = BM + 2, BPAD = BN + 2;
  __shared__ uint4 Asg[8 * APAD];
  __shared__ uint4 Bsg[8 * BPAD];
  const int z = blockIdx.z;
  const bf16* Ap = A + (long long)z * sAh;
  const bf16* Bp = B + (long long)z * sBh;
  const int tid = threadIdx.x;
  const int m0 = blockIdx.y * BM, n0 = blockIdx.x * BN;
  const int lane = tid & 63, wid = tid >> 6;
  const int wm = (wid % WM) * 64, wn = (wid / WM) * 64;
  const int q = lane >> 4, ln = lane & 15;

  uint4 areg[2 * WM], breg[2 * WN];
  const uint4 zero4 = make_uint4(0, 0, 0, 0);

  auto loadTiles = [&](int k0) {
    #pragma unroll
    for (int p = 0; p < 2 * WM; p++) {
      int idx = p * 256 + tid;
      int k8 = idx & 7, m = idx >> 3;
      int gm = m0 + m, gk = k0 + k8 * 8;
      areg[p] = (gm < M && gk < K)
          ? *reinterpret_cast<const uint4*>(Ap + (long long)gm * lda + gk) : zero4;
    }
    #pragma unroll
    for (int p = 0; p < 2 * WN; p++) {
      int idx = p * 256 + tid;
      int k8 = idx & 7, n = idx >> 3;
      int gn = n0 + n, gk = k0 + k8 * 8;
      breg[p] = (gn < N && gk < K)
          ? *reinterpret_cast<const uint4*>(Bp + (long long)gn * ldb + gk) : zero4;
    }
  };
  auto storeTiles = [&]() {
    #pragma unroll
    for (int p = 0; p < 2 * WM; p++) {
      int idx = p * 256 + tid;
      Asg[(idx & 7) * APAD + (idx >> 3)] = areg[p];
    }
    #pragma unroll
    for (int p = 0; p < 2 * WN; p++) {
      int idx = p * 256 + tid;
      Bsg[(idx & 7) * BPAD + (idx >> 3)] = breg[p];
    }
  };

  floatx4 acc[4][4];
  #pragma unroll
  for (int i = 0; i < 4; i++)
    #pragma unroll
    for (int j = 0; j < 4; j++) acc[i][j] = (floatx4){0.f, 0.f, 0.f, 0.f};

  const int nk = (K + 63) >> 6;
  loadTiles(0);
  for (int t = 0; t < nk; t++) {
    __syncthreads();
    storeTiles();
    __syncthreads();
    if (t + 1 < nk) loadTiles((t + 1) * 64);
    #pragma unroll
    for (int ks = 0; ks < 2; ks++) {
      short8 af[4], bfr[4];
      #pragma unroll
      for (int i = 0; i < 4; i++)
        af[i] = *reinterpret_cast<const short8*>(&Asg[(ks * 4 + q) * APAD + wm + i * 16 + ln]);
      #pragma unroll
      for (int j = 0; j < 4; j++)
        bfr[j] = *reinterpret_cast<const short8*>(&Bsg[(ks * 4 + q) * BPAD + wn + j * 16 + ln]);
      #pragma unroll
      for (int i = 0; i < 4; i++)
        #pragma unroll
        for (int j = 0; j < 4; j++)
          acc[i][j] = __builtin_amdgcn_mfma_f32_16x16x32_bf16(af[i], bfr[j], acc[i][j], 0, 0, 0);
    }
  }

  const float* biasz = bias ? bias + z * sBias : nullptr;
  const float* rmz = rowmask ? rowmask + z * sMask : nullptr;
  const int* segz = segidx ? segidx + z * sSeg : nullptr;
  float* ssumz = scatSum ? scatSum + z * sScat : nullptr;
  float* smaxz = scatMax ? scatMax + z * sScat : nullptr;
  float* cF = outF ? outF + (long long)z * sCFh : nullptr;
  bf16*  cB = outB ? outB + (long long)z * sCBh : nullptr;
  #pragma unroll
  for (int i = 0; i < 4; i++) {
    #pragma unroll
    for (int r = 0; r < 4; r++) {
      int gm = m0 + wm + i * 16 + q * 4 + r;
      if (gm >= M) continue;
      float rm = rmz ? rmz[gm] : 1.0f;
      long long r1off = 0;
      if (res1) r1off = (res1skip ? tokrow(gm) : (long long)gm) * ldr1;
      int seg = segz ? segz[gm] : 0;
      #pragma unroll
      for (int j = 0; j < 4; j++) {
        int gn = n0 + wn + j * 16 + ln;
        if (gn >= N) continue;
        float v = acc[i][j][r];
        if (biasz) v += biasz[gn];
        if (act) v = v / (1.0f + __expf(-1.702f * v));  // quick_gelu
        v *= scale * rm;
        if (res1) v += res1[r1off + gn];
        if (res2) v += res2[(long long)gm * ldr2 + gn];
        if (ssumz) {
          atomicAdd(ssumz + (long long)seg * N + gn, v);
          atomicMaxFloat(smaxz + (long long)seg * N + gn, v);
        }
        if (cF) cF[(long long)gm * ldcF + gn] = v;
        if (cB) cB[(long long)gm * ldcB + gn] = __float2bfloat16(v);
      }
    }
  }
}

// fp32 -> bf16 convert (n % 4 == 0)
__global__ void tobf16_kernel(const float* __restrict__ s, bf16* __restrict__ d, int n)
{
  int i = (blockIdx.x * 256 + threadIdx.x) * 4;
  if (i >= n) return;
  float4 v = *reinterpret_cast<const float4*>(s + i);
  d[i]     = __float2bfloat16(v.x);
  d[i + 1] = __float2bfloat16(v.y);
  d[i + 2] = __float2bfloat16(v.z);
  d[i + 3] = __float2bfloat16(v.w);
}

// LayerNorm over C=384, bf16 out; z-batched (per-z in/out/gamma strides)
__global__ __launch_bounds__(128) void ln_kernel(
    const float* __restrict__ in, long long sIn,
    bf16* __restrict__ out, long long sOut,
    const float* __restrict__ g, const float* __restrict__ b, long long sGB,
    int skipcls)
{
  int r = blockIdx.x, z = blockIdx.y;
  long long ir = skipcls ? tokrow(r) : (long long)r;
  const float* x = in + z * sIn + ir * CCH;
  g += z * sGB; b += z * sGB;
  __shared__ float sb[2];
  int c = threadIdx.x;
  float v0 = x[c], v1 = x[c + 128], v2 = x[c + 256];
  float s  = block_reduce_sum<128>(v0 + v1 + v2, sb);
  float s2 = block_reduce_sum<128>(v0 * v0 + v1 * v1 + v2 * v2, sb);
  float m = s * (1.0f / CCH);
  float var = s2 * (1.0f / CCH) - m * m;
  float rstd = rsqrtf(var + 1e-5f);
  bf16* o = out + z * sOut + (long long)r * CCH;
  o[c]       = __float2bfloat16((v0 - m) * rstd * g[c]       + b[c]);
  o[c + 128] = __float2bfloat16((v1 - m) * rstd * g[c + 128] + b[c + 128]);
  o[c + 256] = __float2bfloat16((v2 - m) * rstd * g[c + 256] + b[c + 256]);
}

// V (within qkv, [s][2C + h*64+d]) -> Vt [bh][d][s padded to 1088], zero tail
__global__ __launch_bounds__(256) void vtrans_kernel(
    const bf16* __restrict__ qkv, bf16* __restrict__ Vt)
{
  __shared__ bf16 tile[64][68];
  int bh = blockIdx.y;
  int b = bh / NHEAD, h = bh % NHEAD;
  int s0 = blockIdx.x * 64;
  int dq = (threadIdx.x & 15) * 4;
  int sl = threadIdx.x >> 4;
  #pragma unroll
  for (int p = 0; p < 4; p++) {
    int sloc = sl + p * 16;
    int s = s0 + sloc;
    uint2 v = make_uint2(0, 0);
    if (s < SEQ)
      v = *reinterpret_cast<const uint2*>(
            qkv + ((long long)(b * SEQ + s)) * (3 * CCH) + 2 * CCH + h * DHEAD + dq);
    *reinterpret_cast<uint2*>(&tile[sloc][dq]) = v;
  }
  __syncthreads();
  #pragma unroll
  for (int p = 0; p < 4; p++) {
    int dloc = sl + p * 16;
    int s4 = dq;
    bf16 t0 = tile[s4 + 0][dloc], t1 = tile[s4 + 1][dloc];
    bf16 t2 = tile[s4 + 2][dloc], t3 = tile[s4 + 3][dloc];
    bf16* dst = Vt + ((long long)bh * DHEAD + dloc) * SEQP + s0 + s4;
    dst[0] = t0; dst[1] = t1; dst[2] = t2; dst[3] = t3;
  }
}

// ---------------------------------------------------------------------------
// Flash attention: grid (17 q-tiles, 48 bh). 4 waves x 16 q-rows.
// K/V/P tiles in LDS with 9-granule (144B) row pitch. Online softmax in
// C-layout regs; P round-trips through LDS into A-layout (per-wave rows).
// ---------------------------------------------------------------------------
__global__ __launch_bounds__(256) void flash_kernel(
    const bf16* __restrict__ qkv, const bf16* __restrict__ Vt,
    bf16* __restrict__ O)
{
  __shared__ uint4 Kt[64 * 9];
  __shared__ uint4 Vtt[64 * 9];
  __shared__ uint4 Pt[64 * 9];
  const int bh = blockIdx.y;
  const int b = bh / NHEAD, h = bh % NHEAD;
  const int q0 = blockIdx.x * 64;
  const int tid = threadIdx.x;
  const int lane = tid & 63, w = tid >> 6;
  const int q = lane >> 4, ln = lane & 15;
  const uint4 zero4 = make_uint4(0, 0, 0, 0);

  // Q A-fragments, kept in registers for the whole K loop
  short8 aq[2];
  {
    int qrow = q0 + w * 16 + ln;
    #pragma unroll
    for (int ks = 0; ks < 2; ks++) {
      if (qrow < SEQ)
        aq[ks] = *reinterpret_cast<const short8*>(
            qkv + ((long long)(b * SEQ + qrow)) * (3 * CCH) + h * DHEAD + ks * 32 + q * 8);
      else
        aq[ks] = (short8){0, 0, 0, 0, 0, 0, 0, 0};
    }
  }

  floatx4 oacc[4];
  #pragma unroll
  for (int j = 0; j < 4; j++) oacc[j] = (floatx4){0.f, 0.f, 0.f, 0.f};
  float m_i[4], l_i[4];
  #pragma unroll
  for (int r = 0; r < 4; r++) { m_i[r] = -FLT_MAX; l_i[r] = 0.f; }

  for (int kt = 0; kt < SEQP / 64; kt++) {
    __syncthreads();
    #pragma unroll
    for (int p = 0; p < 2; p++) {
      int g = p * 256 + tid;
      int row = g >> 3, k8 = g & 7;
      int sg = kt * 64 + row;
      uint4 kv = zero4;
      if (sg < SEQ)
        kv = *reinterpret_cast<const uint4*>(
              qkv + ((long long)(b * SEQ + sg)) * (3 * CCH) + CCH + h * DHEAD + k8 * 8);
      Kt[row * 9 + k8] = kv;
      Vtt[row * 9 + k8] = *reinterpret_cast<const uint4*>(
              Vt + ((long long)bh * DHEAD + row) * SEQP + kt * 64 + k8 * 8);
    }
    __syncthreads();

    // S = (Q K^T) / 8
    floatx4 sa[4];
    #pragma unroll
    for (int j = 0; j < 4; j++) sa[j] = (floatx4){0.f, 0.f, 0.f, 0.f};
    #pragma unroll
    for (int ks = 0; ks < 2; ks++) {
      #pragma unroll
      for (int j = 0; j < 4; j++) {
        short8 kb = *reinterpret_cast<const short8*>(&Kt[(j * 16 + ln) * 9 + ks * 4 + q]);
        sa[j] = __builtin_amdgcn_mfma_f32_16x16x32_bf16(aq[ks], kb, sa[j], 0, 0, 0);
      }
    }

    // online softmax per q-row (row = w*16 + q*4 + r; its 64 cols live in
    // accs j=0..3 across the 16 lanes ln of this quarter)
    bf16* pbase = reinterpret_cast<bf16*>(Pt);
    #pragma unroll
    for (int r = 0; r < 4; r++) {
      float mx = -FLT_MAX;
      #pragma unroll
      for (int j = 0; j < 4; j++) {
        float s = sa[j][r] * 0.125f;
        int key = kt * 64 + j * 16 + ln;
        s = (key < SEQ) ? s : -FLT_MAX;
        sa[j][r] = s;
        mx = fmaxf(mx, s);
      }
      #pragma unroll
      for (int off = 1; off < 16; off <<= 1) mx = fmaxf(mx, __shfl_xor(mx, off, 16));
      float mnew = fmaxf(m_i[r], mx);
      float alpha = __expf(m_i[r] - mnew);
      m_i[r] = mnew;
      float rs = 0.f;
      #pragma unroll
      for (int j = 0; j < 4; j++) {
        float p = __expf(sa[j][r] - mnew);
        sa[j][r] = p;
        rs += p;
      }
      #pragma unroll
      for (int off = 1; off < 16; off <<= 1) rs += __shfl_xor(rs, off, 16);
      l_i[r] = l_i[r] * alpha + rs;
      #pragma unroll
      for (int j = 0; j < 4; j++) oacc[j][r] *= alpha;
      bf16* prow = pbase + (w * 16 + q * 4 + r) * 72;
      #pragma unroll
      for (int j = 0; j < 4; j++) prow[j * 16 + ln] = __float2bfloat16(sa[j][r]);
    }
    // P (own wave's rows only -> no barrier needed) @ V
    #pragma unroll
    for (int ks = 0; ks < 2; ks++) {
      short8 ap = *reinterpret_cast<const short8*>(pbase + (w * 16 + ln) * 72 + ks * 32 + q * 8);
      #pragma unroll
      for (int j = 0; j < 4; j++) {
        short8 vb = *reinterpret_cast<const short8*>(&Vtt[(j * 16 + ln) * 9 + ks * 4 + q]);
        oacc[j] = __builtin_amdgcn_mfma_f32_16x16x32_bf16(ap, vb, oacc[j], 0, 0, 0);
      }
    }
  }

  #pragma unroll
  for (int r = 0; r < 4; r++) {
    int qrow = q0 + w * 16 + q * 4 + r;
    if (qrow >= SEQ) continue;
    float inv = 1.0f / l_i[r];
    bf16* orow = O + ((long long)(b * SEQ + qrow)) * CCH + h * DHEAD;
    #pragma unroll
    for (int j = 0; j < 4; j++)
      orow[j * 16 + ln] = __float2bfloat16(oacc[j][r] * inv);
  }
}

// sorted-segment max+mean over cluster ids; one block per segment
__global__ __launch_bounds__(128) void seg1_kernel(
    const float* __restrict__ x2, const int* __restrict__ sorted_idx,
    const int* __restrict__ seg_id, float* __restrict__ s3)
{
  int s = blockIdx.x;
  int lo = 0, hi = NFEAT;
  while (lo < hi) { int mid = (lo + hi) >> 1; if (seg_id[mid] < s) lo = mid + 1; else hi = mid; }
  int start = lo;
  hi = NFEAT;
  while (lo < hi) { int mid = (lo + hi) >> 1; if (seg_id[mid] < s + 1) lo = mid + 1; else hi = mid; }
  int end = lo;
  int cnt = end - start;
  for (int c = threadIdx.x; c < CCH; c += 128) {
    float sum = 0.f, mx = -FLT_MAX;
    for (int r = start; r < end; r++) {
      int n = sorted_idx[r];
      float v = x2[tokrow(n) * CCH + c];
      sum += v; mx = fmaxf(mx, v);
    }
    float u = (cnt > 0 ? mx : 0.f) + sum / fmaxf((float)cnt, 1.0f);
    s3[(long long)s * CCH + c] = u;
  }
}

// per-channel batchnorm stats; z-batched
__global__ __launch_bounds__(256) void bnstats_kernel(
    const float* __restrict__ u, long long sU, int rows,
    float* __restrict__ mean, float* __restrict__ var, long long sMV)
{
  int c = blockIdx.x, z = blockIdx.y;
  u += z * sU; mean += z * sMV; var += z * sMV;
  float s = 0.f, s2 = 0.f;
  for (int r = threadIdx.x; r < rows; r += 256) {
    float v = u[(long long)r * CCH + c];
    s += v; s2 += v * v;
  }
  __shared__ float sb[4];
  s  = block_reduce_sum<256>(s, sb);
  s2 = block_reduce_sum<256>(s2, sb);
  if (threadIdx.x == 0) {
    float m = s / rows;
    mean[c] = m;
    var[c] = s2 / rows - m * m;
  }
}

// BN + exact gelu, result + row L2 norm; z-batched
__global__ __launch_bounds__(128) void bnapply_kernel(
    const float* __restrict__ u, long long sU,
    const float* __restrict__ mean, const float* __restrict__ var, long long sMV,
    const float* __restrict__ g, const float* __restrict__ b, long long sGB,
    float* __restrict__ t, long long sT, float* __restrict__ norms, long long sN)
{
  int r = blockIdx.x, z = blockIdx.y;
  u += z * sU; mean += z * sMV; var += z * sMV; g += z * sGB; b += z * sGB;
  t += z * sT; norms += z * sN;
  float ss = 0.f;
  #pragma unroll
  for (int e = 0; e < 3; e++) {
    int c = threadIdx.x + e * 128;
    float v = u[(long long)r * CCH + c];
    float y = (v - mean[c]) * rsqrtf(var[c] + 1e-5f) * g[c] + b[c];
    float ge = 0.5f * y * (1.0f + erff(y * 0.70710678118654752f));
    t[(long long)r * CCH + c] = ge;
    ss += ge * ge;
  }
  __shared__ float sb[2];
  ss = block_reduce_sum<128>(ss, sb);
  if (threadIdx.x == 0) norms[r] = sqrtf(ss);
}

__global__ void seginit_kernel(float* sum, float* mx, float* cnt)
{
  int idx = blockIdx.x * 256 + threadIdx.x;
  if (idx < NSUP * SEG2 * CCH) { sum[idx] = 0.f; mx[idx] = -FLT_MAX; }
  if (idx < NSUP * SEG2) cnt[idx] = 0.f;
}

__global__ void segcnt_kernel(const int* __restrict__ fgi, float* __restrict__ cnt)
{
  int idx = blockIdx.x * 256 + threadIdx.x;
  if (idx >= NSUP * NFEAT) return;
  int z = idx / NFEAT;
  atomicAdd(cnt + z * SEG2 + fgi[idx], 1.0f);
}

__global__ void segcombine_kernel(float* __restrict__ sum,
                                  const float* __restrict__ mx,
                                  const float* __restrict__ cnt)
{
  int idx = blockIdx.x * 256 + threadIdx.x;
  if (idx >= NSUP * SEG2 * CCH) return;
  int r = idx / CCH;
  float c = cnt[r];
  float m = (c > 0.f) ? mx[idx] : 0.f;
  sum[idx] = m + sum[idx] / fmaxf(c, 1.0f);
}

// cosine-sim weighting + final output (handles CLS copy too)
__global__ __launch_bounds__(128) void final_kernel(
    const float* __restrict__ x2, const float* __restrict__ t3,
    const float* __restrict__ t3norm, const float* __restrict__ t1d,
    const float* __restrict__ t1dnorm, const int* __restrict__ cluster,
    const int* __restrict__ fgi, float* __restrict__ out)
{
  int row = blockIdx.x;
  int b = row / SEQ, gg = row - b * SEQ;
  const float* xr = x2 + (long long)row * CCH;
  float* orow = out + (long long)row * CCH;
  if (gg == 0) {
    for (int c = threadIdx.x; c < CCH; c += 128) orow[c] = xr[c];
    return;
  }
  int n = b * 1024 + gg - 1;
  int c3 = cluster[n];
  const float* a3 = t3 + (long long)c3 * CCH;
  float nb = fmaxf(t3norm[c3], 1e-8f);
  __shared__ float sb[2];
  float w[NSUP];
  const float* rows[NSUP];
  float tot = 0.f;
  for (int i = 0; i < NSUP; i++) {
    int s = fgi[i * NFEAT + n];
    const float* ar = t1d + ((long long)i * SEG2 + s) * CCH;
    rows[i] = ar;
    float d = 0.f;
    for (int c = threadIdx.x; c < CCH; c += 128) d += ar[c] * a3[c];
    d = block_reduce_sum<128>(d, sb);
    float na = fmaxf(t1dnorm[i * SEG2 + s], 1e-8f);
    float cosv = d / (na * nb);
    w[i] = (cosv + 1.0f) * 0.5f;
    tot += w[i];
  }
  float inv = 1.0f / tot;
  for (int c = threadIdx.x; c < CCH; c += 128) {
    float acc = 0.f;
    #pragma unroll
    for (int i = 0; i < NSUP; i++) acc += w[i] * rows[i][c];
    orow[c] = xr[c] + 0.3f * acc * inv;
  }
}

extern "C" void kernel_launch(void* const* d_in, const int* in_sizes, int n_in,
                              void* d_out, int out_size, void* d_ws, size_t ws_size,
                              hipStream_t stream)
{
  const float* x_in   = (const float*)d_in[0];
  const float* maskp  = (const float*)d_in[1];
  const float* ln1_g  = (const float*)d_in[2];
  const float* ln1_b  = (const float*)d_in[3];
  const float* ln2_g  = (const float*)d_in[4];
  const float* ln2_b  = (const float*)d_in[5];
  const float* w_in   = (const float*)d_in[6];
  const float* b_in   = (const float*)d_in[7];
  const float* w_out  = (const float*)d_in[8];
  const float* b_out  = (const float*)d_in[9];
  const float* w_fc   = (const float*)d_in[10];
  const float* b_fc   = (const float*)d_in[11];
  const float* w_proj = (const float*)d_in[12];
  const float* b_proj = (const float*)d_in[13];
  const float* wa1    = (const float*)d_in[14];
  const float* ba1    = (const float*)d_in[15];
  const float* wa2    = (const float*)d_in[16];
  const float* ba2    = (const float*)d_in[17];
  const float* g3     = (const float*)d_in[18];
  const float* b3     = (const float*)d_in[19];
  const float* g1d    = (const float*)d_in[20];
  const float* b1d    = (const float*)d_in[21];
  const float* gn3    = (const float*)d_in[22];
  const float* bn3    = (const float*)d_in[23];
  const float* w_attn1= (const float*)d_in[24];
  const float* b_attn1= (const float*)d_in[25];
  const int* sorted_idx = (const int*)d_in[26];
  const int* seg_id   = (const int*)d_in[27];
  const int* cluster  = (const int*)d_in[28];
  const int* fgi      = (const int*)d_in[29];
  float* out = (float*)d_out;
  char* wsb = (char*)d_ws;

  size_t off = 0;
  auto alloc = [&](size_t bytes) { size_t o = off; off += (bytes + 255) & ~(size_t)255; return o; };
  size_t o_qkv  = alloc((size_t)NTOK * 3 * CCH * 2);            // qkv bf16
  size_t o_Vt   = alloc((size_t)NB * NHEAD * DHEAD * SEQP * 2); // V^T; qkv+Vt reused as fc_bf
  size_t o_hbf  = alloc((size_t)NTOK * CCH * 2);
  size_t o_obf  = alloc((size_t)NTOK * CCH * 2);                // attn out; later ffn_bf
  size_t o_x1   = alloc((size_t)NTOK * CCH * 4);
  size_t o_x2   = alloc((size_t)NTOK * CCH * 4);
  size_t o_ffn  = alloc((size_t)NTOK * CCH * 4);
  size_t o_tbf  = alloc((size_t)NTOK * AAD * 2);
  size_t o_ybf  = alloc((size_t)NSUP * NFEAT * CCH * 2);
  size_t o_s3   = alloc((size_t)MSEG * CCH * 4);
  size_t o_t3   = alloc((size_t)MSEG * CCH * 4);
  size_t o_t3n  = alloc((size_t)MSEG * 4);
  size_t o_mean = alloc((size_t)NSUP * CCH * 4);
  size_t o_var  = alloc((size_t)NSUP * CCH * 4);
  size_t o_ssum = alloc((size_t)NSUP * SEG2 * CCH * 4);
  size_t o_smax = alloc((size_t)NSUP * SEG2 * CCH * 4);
  size_t o_scnt = alloc((size_t)NSUP * SEG2 * 4);
  size_t o_t1d  = alloc((size_t)NSUP * SEG2 * CCH * 4);
  size_t o_t1dn = alloc((size_t)NSUP * SEG2 * 4);
  size_t o_wib  = alloc((size_t)3 * CCH * CCH * 2);
  size_t o_wob  = alloc((size_t)CCH * CCH * 2);
  size_t o_wfb  = alloc((size_t)4 * CCH * CCH * 2);
  size_t o_wpb  = alloc((size_t)CCH * 4 * CCH * 2);
  size_t o_wa1b = alloc((size_t)AAD * CCH * 2);
  size_t o_wa2b = alloc((size_t)CCH * AAD * 2);
  size_t o_watb = alloc((size_t)NSUP * CCH * CCH * 2);

  bf16*  qkv_bf = (bf16*)(wsb + o_qkv);
  bf16*  Vt     = (bf16*)(wsb + o_Vt);
  bf16*  h_bf   = (bf16*)(wsb + o_hbf);
  bf16*  o_bf   = (bf16*)(wsb + o_obf);
  float* x1     = (float*)(wsb + o_x1);
  float* x2     = (float*)(wsb + o_x2);
  float* ffn    = (float*)(wsb + o_ffn);
  bf16*  t_bf   = (bf16*)(wsb + o_tbf);
  bf16*  y_bf   = (bf16*)(wsb + o_ybf);
  float* s3     = (float*)(wsb + o_s3);
  float* t3     = (float*)(wsb + o_t3);
  float* t3n    = (float*)(wsb + o_t3n);
  float* meanb  = (float*)(wsb + o_mean);
  float* varb   = (float*)(wsb + o_var);
  float* ssum   = (float*)(wsb + o_ssum);
  float* smax   = (float*)(wsb + o_smax);
  float* scnt   = (float*)(wsb + o_scnt);
  float* t1d    = (float*)(wsb + o_t1d);
  float* t1dn   = (float*)(wsb + o_t1dn);
  bf16*  w_in_b = (bf16*)(wsb + o_wib);
  bf16*  w_out_b= (bf16*)(wsb + o_wob);
  bf16*  w_fc_b = (bf16*)(wsb + o_wfb);
  bf16*  w_pj_b = (bf16*)(wsb + o_wpb);
  bf16*  wa1_b  = (bf16*)(wsb + o_wa1b);
  bf16*  wa2_b  = (bf16*)(wsb + o_wa2b);
  bf16*  wat_b  = (bf16*)(wsb + o_watb);
  bf16*  fc_bf  = (bf16*)(wsb + o_qkv);  // qkv+Vt dead after attention
  bf16*  ffn_bf = (bf16*)(wsb + o_obf);  // o_bf dead after out-proj

  auto cvt = [&](const float* s, bf16* d, int n) {
    tobf16_kernel<<<(n / 4 + 255) / 256, 256, 0, stream>>>(s, d, n);
  };
  cvt(w_in,    w_in_b, 3 * CCH * CCH);
  cvt(w_out,   w_out_b, CCH * CCH);
  cvt(w_fc,    w_fc_b, 4 * CCH * CCH);
  cvt(w_proj,  w_pj_b, CCH * 4 * CCH);
  cvt(wa1,     wa1_b, AAD * CCH);
  cvt(wa2,     wa2_b, CCH * AAD);
  cvt(w_attn1, wat_b, NSUP * CCH * CCH);

  // 1) ln1
  ln_kernel<<<dim3(NTOK, 1), 128, 0, stream>>>(x_in, 0, h_bf, 0, ln1_g, ln1_b, 0, 0);
  // 2) qkv = ln1 @ w_in^T + b_in
  mgemm_kernel<2, 2><<<dim3(9, 65, 1), 256, 0, stream>>>(
      h_bf, CCH, 0, w_in_b, CCH, 0, nullptr, 0, 0, qkv_bf, 3 * CCH, 0,
      NTOK, 3 * CCH, CCH, b_in, 0, 1.0f, nullptr, nullptr, 0, 0, nullptr, 0,
      0, 0, nullptr, 0, nullptr, nullptr, 0);
  // 3) V transpose, 4) flash attention (all batches/heads in one launch)
  vtrans_kernel<<<dim3(SEQP / 64, NB * NHEAD), 256, 0, stream>>>(qkv_bf, Vt);
  flash_kernel<<<dim3(SEQP / 64, NB * NHEAD), 256, 0, stream>>>(qkv_bf, Vt, o_bf);
  // 5) x1 = x + o @ w_out^T + b_out
  mgemm_kernel<2, 2><<<dim3(3, 65, 1), 256, 0, stream>>>(
      o_bf, CCH, 0, w_out_b, CCH, 0, x1, CCH, 0, nullptr, 0, 0,
      NTOK, CCH, CCH, b_out, 0, 1.0f, nullptr, x_in, CCH, 0, nullptr, 0,
      0, 0, nullptr, 0, nullptr, nullptr, 0);
  // 6) ln2
  ln_kernel<<<dim3(NTOK, 1), 128, 0, stream>>>(x1, 0, h_bf, 0, ln2_g, ln2_b, 0, 0);
  // 7) fc = quick_gelu(ln2 @ w_fc^T + b_fc)
  mgemm_kernel<2, 2><<<dim3(12, 65, 1), 256, 0, stream>>>(
      h_bf, CCH, 0, w_fc_b, CCH, 0, nullptr, 0, 0, fc_bf, 4 * CCH, 0,
      NTOK, 4 * CCH, CCH, b_fc, 1, 1.0f, nullptr, nullptr, 0, 0, nullptr, 0,
      0, 0, nullptr, 0, nullptr, nullptr, 0);
  // 8) x_ffn = fc @ w_proj^T + b_proj
  mgemm_kernel<2, 2><<<dim3(3, 65, 1), 256, 0, stream>>>(
      fc_bf, 4 * CCH, 0, w_pj_b, 4 * CCH, 0, ffn, CCH, 0, ffn_bf, CCH, 0,
      NTOK, CCH, 4 * CCH, b_proj, 0, 1.0f, nullptr, nullptr, 0, 0, nullptr, 0,
      0, 0, nullptr, 0, nullptr, nullptr, 0);
  // 9) t = quick_gelu(x_ffn @ wa1^T + ba1)
  mgemm_kernel<4, 1><<<dim3(1, 33, 1), 256, 0, stream>>>(
      ffn_bf, CCH, 0, wa1_b, CCH, 0, nullptr, 0, 0, t_bf, AAD, 0,
      NTOK, AAD, CCH, ba1, 1, 1.0f, nullptr, nullptr, 0, 0, nullptr, 0,
      0, 0, nullptr, 0, nullptr, nullptr, 0);
  // 10) x2 = x1 + x_ffn + 0.5*(t @ wa2^T + ba2)
  mgemm_kernel<2, 2><<<dim3(3, 65, 1), 256, 0, stream>>>(
      t_bf, AAD, 0, wa2_b, AAD, 0, x2, CCH, 0, nullptr, 0, 0,
      NTOK, CCH, AAD, ba2, 0, 0.5f, nullptr, x1, CCH, 0, ffn, CCH,
      0, 0, nullptr, 0, nullptr, nullptr, 0);
  // 11) cluster pooling -> BN+gelu table t3
  seg1_kernel<<<MSEG, 128, 0, stream>>>(x2, sorted_idx, seg_id, s3);
  bnstats_kernel<<<dim3(CCH, 1), 256, 0, stream>>>(s3, 0, MSEG, meanb, varb, 0);
  bnapply_kernel<<<dim3(MSEG, 1), 128, 0, stream>>>(s3, 0, meanb, varb, 0,
      g3, b3, 0, t3, 0, t3n, 0);
  // 12) six support branches, fully batched over z; scatter fused into GEMM
  seginit_kernel<<<(NSUP * SEG2 * CCH + 255) / 256, 256, 0, stream>>>(ssum, smax, scnt);
  segcnt_kernel<<<(NSUP * NFEAT + 255) / 256, 256, 0, stream>>>(fgi, scnt);
  ln_kernel<<<dim3(NFEAT, NSUP), 128, 0, stream>>>(
      x2, 0, y_bf, (long long)NFEAT * CCH, gn3, bn3, CCH, 1);
  mgemm_kernel<2, 2><<<dim3(3, 64, NSUP), 256, 0, stream>>>(
      y_bf, CCH, (long long)NFEAT * CCH, wat_b, CCH, (long long)CCH * CCH,
      nullptr, 0, 0, nullptr, 0, 0,
      NFEAT, CCH, CCH, b_attn1, 0, 1.0f, maskp, x2, CCH, 1, nullptr, 0,
      CCH, NFEAT, fgi, NFEAT, ssum, smax, (long long)SEG2 * CCH);
  segcombine_kernel<<<(NSUP * SEG2 * CCH + 255) / 256, 256, 0, stream>>>(ssum, smax, scnt);
  bnstats_kernel<<<dim3(CCH, NSUP), 256, 0, stream>>>(
      ssum, (long long)SEG2 * CCH, SEG2, meanb, varb, CCH);
  bnapply_kernel<<<dim3(SEG2, NSUP), 128, 0, stream>>>(
      ssum, (long long)SEG2 * CCH, meanb, varb, CCH,
      g1d, b1d, CCH, t1d, (long long)SEG2 * CCH, t1dn, SEG2);
  // 13) cosine weighting + output
  final_kernel<<<NTOK, 128, 0, stream>>>(x2, t3, t3n, t1d, t1dn, cluster, fgi, out);
}

// Round 4
// 695.566 us; speedup vs baseline: 3.5902x; 1.5165x over previous
//
#include <hip/hip_runtime.h>
#include <hip/hip_bf16.h>
#include <float.h>
#include <math.h>

#define NB 8
#define CCH 384
#define NHEAD 6
#define DHEAD 64
#define AAD 48
#define MSEG 1024
#define NSUP 6
#define NTOK 8200
#define NFEAT 8192
#define SEG2 1536
#define SEQ 1025
#define SEQP 1088

typedef __hip_bfloat16 bf16;
typedef __attribute__((ext_vector_type(8))) short short8;
typedef __attribute__((ext_vector_type(4))) float floatx4;

// feat row n (0..8191) -> row index in (B,1025,C) token array, skipping CLS
static __device__ __forceinline__ long long tokrow(int n) {
  return (long long)n + (n >> 10) + 1;
}

template<int NT>
static __device__ __forceinline__ float block_reduce_sum(float v, float* s) {
  #pragma unroll
  for (int off = 32; off > 0; off >>= 1) v += __shfl_down(v, off, 64);
  int lane = threadIdx.x & 63, wid = threadIdx.x >> 6;
  if (lane == 0) s[wid] = v;
  __syncthreads();
  if (threadIdx.x == 0) {
    float t = s[0];
    #pragma unroll
    for (int w = 1; w < NT / 64; w++) t += s[w];
    s[0] = t;
  }
  __syncthreads();
  float r = s[0];
  __syncthreads();
  return r;
}

// async global->LDS 16B copy (width=16 verified on gfx950, learn_hip m97)
static __device__ __forceinline__ void async_copy16(void* lds, const void* g) {
  __builtin_amdgcn_global_load_lds(
      (const __attribute__((address_space(1))) unsigned int*)g,
      (__attribute__((address_space(3))) unsigned int*)lds, 16, 0, 0);
}

// ---------------------------------------------------------------------------
// MFMA bf16 GEMM:  C[m,n] = sum_k A[m,k] * Bt[n,k]   (Bt stored N x K)
// 4 waves, wave tile 64x64 via 16x16x32 bf16 MFMA. BK=64.
// LDS: linear granule layout [row][8 granules of 16B], XOR-swizzled
// (granule g holds global granule g ^ (row&7)) -> global_load_lds-compatible
// AND 2-way-max bank aliasing on ds_read_b128 (free per m136).
// Fast path (async DMA) when the tile is fully in-bounds and K%64==0;
// slow path (register staging, same layout) otherwise.
// ---------------------------------------------------------------------------
template<int WM, int WN>
__global__ __launch_bounds__(256) void mgemm_kernel(
    const bf16* __restrict__ A, int lda, long long sAh,
    const bf16* __restrict__ B, int ldb, long long sBh,
    float* __restrict__ outF, int ldcF, long long sCFh,
    bf16* __restrict__ outB, int ldcB, long long sCBh,
    int M, int N, int K,
    const float* __restrict__ bias, long long sBias, int act, float scale,
    const float* __restrict__ rowmask, long long sMask,
    const float* __restrict__ res1, int ldr1, int res1skip,
    const float* __restrict__ res2, int ldr2)
{
  constexpr int BM = WM * 64, BN = WN * 64;
  __shared__ uint4 Asg[BM * 8];
  __shared__ uint4 Bsg[BN * 8];
  const int z = blockIdx.z;
  const bf16* Ap = A + (long long)z * sAh;
  const bf16* Bp = B + (long long)z * sBh;
  const int tid = threadIdx.x;
  const int m0 = blockIdx.y * BM, n0 = blockIdx.x * BN;
  const int lane = tid & 63, wid = tid >> 6;
  const int wm = (wid % WM) * 64, wn = (wid / WM) * 64;
  const int q = lane >> 4, ln = lane & 15;
  const uint4 zero4 = make_uint4(0, 0, 0, 0);

  const bool fastK = ((K & 63) == 0);
  const bool fastA = fastK && (m0 + BM <= M);
  const bool fastB = fastK && (n0 + BN <= N);

  floatx4 acc[4][4];
  #pragma unroll
  for (int i = 0; i < 4; i++)
    #pragma unroll
    for (int j = 0; j < 4; j++) acc[i][j] = (floatx4){0.f, 0.f, 0.f, 0.f};

  const int nk = (K + 63) >> 6;
  for (int t = 0; t < nk; t++) {
    const int k0 = t * 64;
    __syncthreads();
    if (fastA) {
      #pragma unroll
      for (int p = 0; p < 2 * WM; p++) {
        int idx = p * 256 + tid;
        int row = idx >> 3, g = idx & 7;
        int gs = g ^ (row & 7);
        async_copy16(&Asg[p * 256 + wid * 64],
                     Ap + (long long)(m0 + row) * lda + k0 + gs * 8);
      }
    } else {
      #pragma unroll
      for (int p = 0; p < 2 * WM; p++) {
        int idx = p * 256 + tid;
        int row = idx >> 3, g = idx & 7;
        int gs = g ^ (row & 7);
        int gm = m0 + row, gk = k0 + gs * 8;
        uint4 v = zero4;
        if (gm < M && gk < K)
          v = *reinterpret_cast<const uint4*>(Ap + (long long)gm * lda + gk);
        Asg[idx] = v;
      }
    }
    if (fastB) {
      #pragma unroll
      for (int p = 0; p < 2 * WN; p++) {
        int idx = p * 256 + tid;
        int row = idx >> 3, g = idx & 7;
        int gs = g ^ (row & 7);
        async_copy16(&Bsg[p * 256 + wid * 64],
                     Bp + (long long)(n0 + row) * ldb + k0 + gs * 8);
      }
    } else {
      #pragma unroll
      for (int p = 0; p < 2 * WN; p++) {
        int idx = p * 256 + tid;
        int row = idx >> 3, g = idx & 7;
        int gs = g ^ (row & 7);
        int gn = n0 + row, gk = k0 + gs * 8;
        uint4 v = zero4;
        if (gn < N && gk < K)
          v = *reinterpret_cast<const uint4*>(Bp + (long long)gn * ldb + gk);
        Bsg[idx] = v;
      }
    }
    asm volatile("s_waitcnt vmcnt(0)" ::: "memory");
    __syncthreads();
    #pragma unroll
    for (int ks = 0; ks < 2; ks++) {
      short8 af[4], bfr[4];
      #pragma unroll
      for (int i = 0; i < 4; i++) {
        int row = wm + i * 16 + ln;
        af[i] = *reinterpret_cast<const short8*>(
            &Asg[row * 8 + ((ks * 4 + q) ^ (ln & 7))]);
      }
      #pragma unroll
      for (int j = 0; j < 4; j++) {
        int row = wn + j * 16 + ln;
        bfr[j] = *reinterpret_cast<const short8*>(
            &Bsg[row * 8 + ((ks * 4 + q) ^ (ln & 7))]);
      }
      #pragma unroll
      for (int i = 0; i < 4; i++)
        #pragma unroll
        for (int j = 0; j < 4; j++)
          acc[i][j] = __builtin_amdgcn_mfma_f32_16x16x32_bf16(af[i], bfr[j], acc[i][j], 0, 0, 0);
    }
  }

  const float* biasz = bias ? bias + z * sBias : nullptr;
  const float* rmz = rowmask ? rowmask + z * sMask : nullptr;
  float* cF = outF ? outF + (long long)z * sCFh : nullptr;
  bf16*  cB = outB ? outB + (long long)z * sCBh : nullptr;
  #pragma unroll
  for (int i = 0; i < 4; i++) {
    #pragma unroll
    for (int r = 0; r < 4; r++) {
      int gm = m0 + wm + i * 16 + q * 4 + r;
      if (gm >= M) continue;
      float rm = rmz ? rmz[gm] : 1.0f;
      long long r1off = 0;
      if (res1) r1off = (res1skip ? tokrow(gm) : (long long)gm) * ldr1;
      #pragma unroll
      for (int j = 0; j < 4; j++) {
        int gn = n0 + wn + j * 16 + ln;
        if (gn >= N) continue;
        float v = acc[i][j][r];
        if (biasz) v += biasz[gn];
        if (act) v = v / (1.0f + __expf(-1.702f * v));  // quick_gelu
        v *= scale * rm;
        if (res1) v += res1[r1off + gn];
        if (res2) v += res2[(long long)gm * ldr2 + gn];
        if (cF) cF[(long long)gm * ldcF + gn] = v;
        if (cB) cB[(long long)gm * ldcB + gn] = __float2bfloat16(v);
      }
    }
  }
}

// fp32 -> bf16 convert (n % 4 == 0)
__global__ void tobf16_kernel(const float* __restrict__ s, bf16* __restrict__ d, int n)
{
  int i = (blockIdx.x * 256 + threadIdx.x) * 4;
  if (i >= n) return;
  float4 v = *reinterpret_cast<const float4*>(s + i);
  d[i]     = __float2bfloat16(v.x);
  d[i + 1] = __float2bfloat16(v.y);
  d[i + 2] = __float2bfloat16(v.z);
  d[i + 3] = __float2bfloat16(v.w);
}

// W'[z][n][k] = bf16(W[z][n][k] * g[z][k])   (cols == CCH)
__global__ void scalecvt_kernel(const float* __restrict__ W,
                                const float* __restrict__ g, long long sG,
                                bf16* __restrict__ out, int n4)
{
  int z = blockIdx.y;
  int i = (blockIdx.x * 256 + threadIdx.x) * 4;
  if (i >= n4) return;
  const float* Wz = W + (long long)z * n4;
  const float* gz = g + z * sG;
  bf16* oz = out + (long long)z * n4;
  int k = i % CCH;
  float4 v = *reinterpret_cast<const float4*>(Wz + i);
  oz[i]     = __float2bfloat16(v.x * gz[k]);
  oz[i + 1] = __float2bfloat16(v.y * gz[k + 1]);
  oz[i + 2] = __float2bfloat16(v.z * gz[k + 2]);
  oz[i + 3] = __float2bfloat16(v.w * gz[k + 3]);
}

// out[z][n] = b[z][n] + sum_k beta[z][k] * W[z][n][k]   (one wave per n)
__global__ __launch_bounds__(64) void foldbias_kernel(
    const float* __restrict__ W, const float* __restrict__ b,
    const float* __restrict__ beta, long long sBeta,
    float* __restrict__ out)
{
  int n = blockIdx.x, z = blockIdx.y, rows = gridDim.x;
  const float* Wr = W + ((long long)z * rows + n) * CCH;
  const float* bz = beta + z * sBeta;
  float s = 0.f;
  for (int k = threadIdx.x; k < CCH; k += 64) s += Wr[k] * bz[k];
  #pragma unroll
  for (int off = 32; off > 0; off >>= 1) s += __shfl_down(s, off, 64);
  if (threadIdx.x == 0) out[(long long)z * rows + n] = b[(long long)z * rows + n] + s;
}

// plain LayerNorm (no affine) over C=384, bf16 out
__global__ __launch_bounds__(128) void norm_kernel(
    const float* __restrict__ in, bf16* __restrict__ out, int skipcls)
{
  int r = blockIdx.x;
  long long ir = skipcls ? tokrow(r) : (long long)r;
  const float* x = in + ir * CCH;
  __shared__ float sb[2];
  int c = threadIdx.x;
  float v0 = x[c], v1 = x[c + 128], v2 = x[c + 256];
  float s  = block_reduce_sum<128>(v0 + v1 + v2, sb);
  float s2 = block_reduce_sum<128>(v0 * v0 + v1 * v1 + v2 * v2, sb);
  float m = s * (1.0f / CCH);
  float var = s2 * (1.0f / CCH) - m * m;
  float rstd = rsqrtf(var + 1e-5f);
  bf16* o = out + (long long)r * CCH;
  o[c]       = __float2bfloat16((v0 - m) * rstd);
  o[c + 128] = __float2bfloat16((v1 - m) * rstd);
  o[c + 256] = __float2bfloat16((v2 - m) * rstd);
}

// V (within qkv, [s][2C + h*64+d]) -> Vt [bh][d][s padded to 1088], zero tail
__global__ __launch_bounds__(256) void vtrans_kernel(
    const bf16* __restrict__ qkv, bf16* __restrict__ Vt)
{
  __shared__ bf16 tile[64][68];
  int bh = blockIdx.y;
  int b = bh / NHEAD, h = bh % NHEAD;
  int s0 = blockIdx.x * 64;
  int dq = (threadIdx.x & 15) * 4;
  int sl = threadIdx.x >> 4;
  #pragma unroll
  for (int p = 0; p < 4; p++) {
    int sloc = sl + p * 16;
    int s = s0 + sloc;
    uint2 v = make_uint2(0, 0);
    if (s < SEQ)
      v = *reinterpret_cast<const uint2*>(
            qkv + ((long long)(b * SEQ + s)) * (3 * CCH) + 2 * CCH + h * DHEAD + dq);
    *reinterpret_cast<uint2*>(&tile[sloc][dq]) = v;
  }
  __syncthreads();
  #pragma unroll
  for (int p = 0; p < 4; p++) {
    int dloc = sl + p * 16;
    int s4 = dq;
    bf16 t0 = tile[s4 + 0][dloc], t1 = tile[s4 + 1][dloc];
    bf16 t2 = tile[s4 + 2][dloc], t3 = tile[s4 + 3][dloc];
    bf16* dst = Vt + ((long long)bh * DHEAD + dloc) * SEQP + s0 + s4;
    dst[0] = t0; dst[1] = t1; dst[2] = t2; dst[3] = t3;
  }
}

// ---------------------------------------------------------------------------
// Flash attention: grid (17 q-tiles, 48 bh). 4 waves x 16 q-rows.
// ---------------------------------------------------------------------------
__global__ __launch_bounds__(256) void flash_kernel(
    const bf16* __restrict__ qkv, const bf16* __restrict__ Vt,
    bf16* __restrict__ O)
{
  __shared__ uint4 Kt[64 * 9];
  __shared__ uint4 Vtt[64 * 9];
  __shared__ uint4 Pt[64 * 9];
  const int bh = blockIdx.y;
  const int b = bh / NHEAD, h = bh % NHEAD;
  const int q0 = blockIdx.x * 64;
  const int tid = threadIdx.x;
  const int lane = tid & 63, w = tid >> 6;
  const int q = lane >> 4, ln = lane & 15;
  const uint4 zero4 = make_uint4(0, 0, 0, 0);

  short8 aq[2];
  {
    int qrow = q0 + w * 16 + ln;
    #pragma unroll
    for (int ks = 0; ks < 2; ks++) {
      if (qrow < SEQ)
        aq[ks] = *reinterpret_cast<const short8*>(
            qkv + ((long long)(b * SEQ + qrow)) * (3 * CCH) + h * DHEAD + ks * 32 + q * 8);
      else
        aq[ks] = (short8){0, 0, 0, 0, 0, 0, 0, 0};
    }
  }

  floatx4 oacc[4];
  #pragma unroll
  for (int j = 0; j < 4; j++) oacc[j] = (floatx4){0.f, 0.f, 0.f, 0.f};
  float m_i[4], l_i[4];
  #pragma unroll
  for (int r = 0; r < 4; r++) { m_i[r] = -FLT_MAX; l_i[r] = 0.f; }

  for (int kt = 0; kt < SEQP / 64; kt++) {
    __syncthreads();
    #pragma unroll
    for (int p = 0; p < 2; p++) {
      int g = p * 256 + tid;
      int row = g >> 3, k8 = g & 7;
      int sg = kt * 64 + row;
      uint4 kv = zero4;
      if (sg < SEQ)
        kv = *reinterpret_cast<const uint4*>(
              qkv + ((long long)(b * SEQ + sg)) * (3 * CCH) + CCH + h * DHEAD + k8 * 8);
      Kt[row * 9 + k8] = kv;
      Vtt[row * 9 + k8] = *reinterpret_cast<const uint4*>(
              Vt + ((long long)bh * DHEAD + row) * SEQP + kt * 64 + k8 * 8);
    }
    __syncthreads();

    floatx4 sa[4];
    #pragma unroll
    for (int j = 0; j < 4; j++) sa[j] = (floatx4){0.f, 0.f, 0.f, 0.f};
    #pragma unroll
    for (int ks = 0; ks < 2; ks++) {
      #pragma unroll
      for (int j = 0; j < 4; j++) {
        short8 kb = *reinterpret_cast<const short8*>(&Kt[(j * 16 + ln) * 9 + ks * 4 + q]);
        sa[j] = __builtin_amdgcn_mfma_f32_16x16x32_bf16(aq[ks], kb, sa[j], 0, 0, 0);
      }
    }

    bf16* pbase = reinterpret_cast<bf16*>(Pt);
    #pragma unroll
    for (int r = 0; r < 4; r++) {
      float mx = -FLT_MAX;
      #pragma unroll
      for (int j = 0; j < 4; j++) {
        float s = sa[j][r] * 0.125f;
        int key = kt * 64 + j * 16 + ln;
        s = (key < SEQ) ? s : -FLT_MAX;
        sa[j][r] = s;
        mx = fmaxf(mx, s);
      }
      #pragma unroll
      for (int off = 1; off < 16; off <<= 1) mx = fmaxf(mx, __shfl_xor(mx, off, 16));
      float mnew = fmaxf(m_i[r], mx);
      float alpha = __expf(m_i[r] - mnew);
      m_i[r] = mnew;
      float rs = 0.f;
      #pragma unroll
      for (int j = 0; j < 4; j++) {
        float p = __expf(sa[j][r] - mnew);
        sa[j][r] = p;
        rs += p;
      }
      #pragma unroll
      for (int off = 1; off < 16; off <<= 1) rs += __shfl_xor(rs, off, 16);
      l_i[r] = l_i[r] * alpha + rs;
      #pragma unroll
      for (int j = 0; j < 4; j++) oacc[j][r] *= alpha;
      bf16* prow = pbase + (w * 16 + q * 4 + r) * 72;
      #pragma unroll
      for (int j = 0; j < 4; j++) prow[j * 16 + ln] = __float2bfloat16(sa[j][r]);
    }
    #pragma unroll
    for (int ks = 0; ks < 2; ks++) {
      short8 ap = *reinterpret_cast<const short8*>(pbase + (w * 16 + ln) * 72 + ks * 32 + q * 8);
      #pragma unroll
      for (int j = 0; j < 4; j++) {
        short8 vb = *reinterpret_cast<const short8*>(&Vtt[(j * 16 + ln) * 9 + ks * 4 + q]);
        oacc[j] = __builtin_amdgcn_mfma_f32_16x16x32_bf16(ap, vb, oacc[j], 0, 0, 0);
      }
    }
  }

  #pragma unroll
  for (int r = 0; r < 4; r++) {
    int qrow = q0 + w * 16 + q * 4 + r;
    if (qrow >= SEQ) continue;
    float inv = 1.0f / l_i[r];
    bf16* orow = O + ((long long)(b * SEQ + qrow)) * CCH + h * DHEAD;
    #pragma unroll
    for (int j = 0; j < 4; j++)
      orow[j * 16 + ln] = __float2bfloat16(oacc[j][r] * inv);
  }
}

// sorted-segment max+mean over cluster ids; one block per segment
__global__ __launch_bounds__(128) void seg1_kernel(
    const float* __restrict__ x2, const int* __restrict__ sorted_idx,
    const int* __restrict__ seg_id, float* __restrict__ s3)
{
  int s = blockIdx.x;
  int lo = 0, hi = NFEAT;
  while (lo < hi) { int mid = (lo + hi) >> 1; if (seg_id[mid] < s) lo = mid + 1; else hi = mid; }
  int start = lo;
  hi = NFEAT;
  while (lo < hi) { int mid = (lo + hi) >> 1; if (seg_id[mid] < s + 1) lo = mid + 1; else hi = mid; }
  int end = lo;
  int cnt = end - start;
  for (int c = threadIdx.x; c < CCH; c += 128) {
    float sum = 0.f, mx = -FLT_MAX;
    for (int r = start; r < end; r++) {
      int n = sorted_idx[r];
      float v = x2[tokrow(n) * CCH + c];
      sum += v; mx = fmaxf(mx, v);
    }
    float u = (cnt > 0 ? mx : 0.f) + sum / fmaxf((float)cnt, 1.0f);
    s3[(long long)s * CCH + c] = u;
  }
}

// counting sort over flat_grid_index: hist -> scan -> place
__global__ void hist0_kernel(int* __restrict__ cnt)
{
  int idx = blockIdx.x * 256 + threadIdx.x;
  if (idx < NSUP * SEG2) cnt[idx] = 0;
}
__global__ void hist_kernel(const int* __restrict__ fgi, int* __restrict__ cnt)
{
  int idx = blockIdx.x * 256 + threadIdx.x;
  if (idx >= NSUP * NFEAT) return;
  int z = idx >> 13;
  atomicAdd(&cnt[z * SEG2 + fgi[idx]], 1);
}
__global__ __launch_bounds__(256) void scan_kernel(
    const int* __restrict__ cnt, int* __restrict__ base, int* __restrict__ cur)
{
  int z = blockIdx.x, t = threadIdx.x;
  __shared__ int sdata[256];
  const int* c = cnt + z * SEG2;
  int loc[6]; int s = 0;
  #pragma unroll
  for (int e = 0; e < 6; e++) { loc[e] = s; s += c[t * 6 + e]; }
  sdata[t] = s;
  __syncthreads();
  for (int off = 1; off < 256; off <<= 1) {
    int v = (t >= off) ? sdata[t - off] : 0;
    __syncthreads();
    sdata[t] += v;
    __syncthreads();
  }
  int pre = (t > 0) ? sdata[t - 1] : 0;
  #pragma unroll
  for (int e = 0; e < 6; e++) {
    int b = pre + loc[e];
    base[z * SEG2 + t * 6 + e] = b;
    cur[z * SEG2 + t * 6 + e] = b;
  }
}
__global__ void place_kernel(const int* __restrict__ fgi, int* __restrict__ cur,
                             int* __restrict__ order)
{
  int idx = blockIdx.x * 256 + threadIdx.x;
  if (idx >= NSUP * NFEAT) return;
  int z = idx >> 13, n = idx & (NFEAT - 1);
  int s = fgi[idx];
  int pos = atomicAdd(&cur[z * SEG2 + s], 1);
  order[z * NFEAT + pos] = n;
}

// gather-based segment max+mean from fx (bf16) -> u[z][s][c]
__global__ __launch_bounds__(128) void seg2_kernel(
    const bf16* __restrict__ fx, const int* __restrict__ base,
    const int* __restrict__ cnt, const int* __restrict__ order,
    float* __restrict__ u)
{
  int s = blockIdx.x, z = blockIdx.y;
  int st = base[z * SEG2 + s], c = cnt[z * SEG2 + s];
  const int* ord = order + z * NFEAT;
  const bf16* fz = fx + (long long)z * NFEAT * CCH;
  for (int ch = threadIdx.x; ch < CCH; ch += 128) {
    float sum = 0.f, mx = -FLT_MAX;
    for (int r = 0; r < c; r++) {
      float v = __bfloat162float(fz[(long long)ord[st + r] * CCH + ch]);
      sum += v; mx = fmaxf(mx, v);
    }
    u[((long long)z * SEG2 + s) * CCH + ch] = (c > 0 ? mx : 0.f) + sum / fmaxf((float)c, 1.0f);
  }
}

// per-channel batchnorm stats; z-batched
__global__ __launch_bounds__(256) void bnstats_kernel(
    const float* __restrict__ u, long long sU, int rows,
    float* __restrict__ mean, float* __restrict__ var, long long sMV)
{
  int c = blockIdx.x, z = blockIdx.y;
  u += z * sU; mean += z * sMV; var += z * sMV;
  float s = 0.f, s2 = 0.f;
  for (int r = threadIdx.x; r < rows; r += 256) {
    float v = u[(long long)r * CCH + c];
    s += v; s2 += v * v;
  }
  __shared__ float sb[4];
  s  = block_reduce_sum<256>(s, sb);
  s2 = block_reduce_sum<256>(s2, sb);
  if (threadIdx.x == 0) {
    float m = s / rows;
    mean[c] = m;
    var[c] = s2 / rows - m * m;
  }
}

// BN + exact gelu, result + row L2 norm; z-batched
__global__ __launch_bounds__(128) void bnapply_kernel(
    const float* __restrict__ u, long long sU,
    const float* __restrict__ mean, const float* __restrict__ var, long long sMV,
    const float* __restrict__ g, const float* __restrict__ b, long long sGB,
    float* __restrict__ t, long long sT, float* __restrict__ norms, long long sN)
{
  int r = blockIdx.x, z = blockIdx.y;
  u += z * sU; mean += z * sMV; var += z * sMV; g += z * sGB; b += z * sGB;
  t += z * sT; norms += z * sN;
  float ss = 0.f;
  #pragma unroll
  for (int e = 0; e < 3; e++) {
    int c = threadIdx.x + e * 128;
    float v = u[(long long)r * CCH + c];
    float y = (v - mean[c]) * rsqrtf(var[c] + 1e-5f) * g[c] + b[c];
    float ge = 0.5f * y * (1.0f + erff(y * 0.70710678118654752f));
    t[(long long)r * CCH + c] = ge;
    ss += ge * ge;
  }
  __shared__ float sb[2];
  ss = block_reduce_sum<128>(ss, sb);
  if (threadIdx.x == 0) norms[r] = sqrtf(ss);
}

// cosine-sim weighting + final output (handles CLS copy too)
__global__ __launch_bounds__(128) void final_kernel(
    const float* __restrict__ x2, const float* __restrict__ t3,
    const float* __restrict__ t3norm, const float* __restrict__ t1d,
    const float* __restrict__ t1dnorm, const int* __restrict__ cluster,
    const int* __restrict__ fgi, float* __restrict__ out)
{
  int row = blockIdx.x;
  int b = row / SEQ, gg = row - b * SEQ;
  const float* xr = x2 + (long long)row * CCH;
  float* orow = out + (long long)row * CCH;
  if (gg == 0) {
    for (int c = threadIdx.x; c < CCH; c += 128) orow[c] = xr[c];
    return;
  }
  int n = b * 1024 + gg - 1;
  int c3 = cluster[n];
  const float* a3 = t3 + (long long)c3 * CCH;
  float nb = fmaxf(t3norm[c3], 1e-8f);
  __shared__ float sb[2];
  float w[NSUP];
  const float* rows[NSUP];
  float tot = 0.f;
  for (int i = 0; i < NSUP; i++) {
    int s = fgi[i * NFEAT + n];
    const float* ar = t1d + ((long long)i * SEG2 + s) * CCH;
    rows[i] = ar;
    float d = 0.f;
    for (int c = threadIdx.x; c < CCH; c += 128) d += ar[c] * a3[c];
    d = block_reduce_sum<128>(d, sb);
    float na = fmaxf(t1dnorm[i * SEG2 + s], 1e-8f);
    float cosv = d / (na * nb);
    w[i] = (cosv + 1.0f) * 0.5f;
    tot += w[i];
  }
  float inv = 1.0f / tot;
  for (int c = threadIdx.x; c < CCH; c += 128) {
    float acc = 0.f;
    #pragma unroll
    for (int i = 0; i < NSUP; i++) acc += w[i] * rows[i][c];
    orow[c] = xr[c] + 0.3f * acc * inv;
  }
}

extern "C" void kernel_launch(void* const* d_in, const int* in_sizes, int n_in,
                              void* d_out, int out_size, void* d_ws, size_t ws_size,
                              hipStream_t stream)
{
  const float* x_in   = (const float*)d_in[0];
  const float* maskp  = (const float*)d_in[1];
  const float* ln1_g  = (const float*)d_in[2];
  const float* ln1_b  = (const float*)d_in[3];
  const float* ln2_g  = (const float*)d_in[4];
  const float* ln2_b  = (const float*)d_in[5];
  const float* w_in   = (const float*)d_in[6];
  const float* b_in   = (const float*)d_in[7];
  const float* w_out  = (const float*)d_in[8];
  const float* b_out  = (const float*)d_in[9];
  const float* w_fc   = (const float*)d_in[10];
  const float* b_fc   = (const float*)d_in[11];
  const float* w_proj = (const float*)d_in[12];
  const float* b_proj = (const float*)d_in[13];
  const float* wa1    = (const float*)d_in[14];
  const float* ba1    = (const float*)d_in[15];
  const float* wa2    = (const float*)d_in[16];
  const float* ba2    = (const float*)d_in[17];
  const float* g3     = (const float*)d_in[18];
  const float* b3     = (const float*)d_in[19];
  const float* g1d    = (const float*)d_in[20];
  const float* b1d    = (const float*)d_in[21];
  const float* gn3    = (const float*)d_in[22];
  const float* bn3    = (const float*)d_in[23];
  const float* w_attn1= (const float*)d_in[24];
  const float* b_attn1= (const float*)d_in[25];
  const int* sorted_idx = (const int*)d_in[26];
  const int* seg_id   = (const int*)d_in[27];
  const int* cluster  = (const int*)d_in[28];
  const int* fgi      = (const int*)d_in[29];
  float* out = (float*)d_out;
  char* wsb = (char*)d_ws;

  size_t off = 0;
  auto alloc = [&](size_t bytes) { size_t o = off; off += (bytes + 255) & ~(size_t)255; return o; };
  size_t o_qkv  = alloc((size_t)NTOK * 3 * CCH * 2);            // qkv bf16
  size_t o_Vt   = alloc((size_t)NB * NHEAD * DHEAD * SEQP * 2); // Vt; qkv+Vt reused as fc_bf
  size_t o_hbf  = alloc((size_t)NTOK * CCH * 2);                // norm out bf16 (reused 3x)
  size_t o_obf  = alloc((size_t)NTOK * CCH * 2);                // attn out; later ffn_bf
  size_t o_x1   = alloc((size_t)NTOK * CCH * 4);
  size_t o_x2   = alloc((size_t)NTOK * CCH * 4);
  size_t o_ffn  = alloc((size_t)NTOK * CCH * 4);
  size_t o_tbf  = alloc((size_t)NTOK * AAD * 2);
  size_t o_fx   = alloc((size_t)NSUP * NFEAT * CCH * 2);        // branch out bf16
  size_t o_s3   = alloc((size_t)MSEG * CCH * 4);
  size_t o_t3   = alloc((size_t)MSEG * CCH * 4);
  size_t o_t3n  = alloc((size_t)MSEG * 4);
  size_t o_mean = alloc((size_t)NSUP * CCH * 4);
  size_t o_var  = alloc((size_t)NSUP * CCH * 4);
  size_t o_ssum = alloc((size_t)NSUP * SEG2 * CCH * 4);
  size_t o_t1d  = alloc((size_t)NSUP * SEG2 * CCH * 4);
  size_t o_t1dn = alloc((size_t)NSUP * SEG2 * 4);
  size_t o_cnt  = alloc((size_t)NSUP * SEG2 * 4);
  size_t o_base = alloc((size_t)NSUP * SEG2 * 4);
  size_t o_cur  = alloc((size_t)NSUP * SEG2 * 4);
  size_t o_ord  = alloc((size_t)NSUP * NFEAT * 4);
  size_t o_wib  = alloc((size_t)3 * CCH * CCH * 2);
  size_t o_wob  = alloc((size_t)CCH * CCH * 2);
  size_t o_wfb  = alloc((size_t)4 * CCH * CCH * 2);
  size_t o_wpb  = alloc((size_t)CCH * 4 * CCH * 2);
  size_t o_wa1b = alloc((size_t)AAD * CCH * 2);
  size_t o_wa2b = alloc((size_t)CCH * AAD * 2);
  size_t o_watb = alloc((size_t)NSUP * CCH * CCH * 2);
  size_t o_bib  = alloc((size_t)3 * CCH * 4);
  size_t o_bfb  = alloc((size_t)4 * CCH * 4);
  size_t o_bab  = alloc((size_t)NSUP * CCH * 4);

  bf16*  qkv_bf = (bf16*)(wsb + o_qkv);
  bf16*  Vt     = (bf16*)(wsb + o_Vt);
  bf16*  h_bf   = (bf16*)(wsb + o_hbf);
  bf16*  o_bf   = (bf16*)(wsb + o_obf);
  float* x1     = (float*)(wsb + o_x1);
  float* x2     = (float*)(wsb + o_x2);
  float* ffn    = (float*)(wsb + o_ffn);
  bf16*  t_bf   = (bf16*)(wsb + o_tbf);
  bf16*  fx     = (bf16*)(wsb + o_fx);
  float* s3     = (float*)(wsb + o_s3);
  float* t3     = (float*)(wsb + o_t3);
  float* t3n    = (float*)(wsb + o_t3n);
  float* meanb  = (float*)(wsb + o_mean);
  float* varb   = (float*)(wsb + o_var);
  float* ssum   = (float*)(wsb + o_ssum);
  float* t1d    = (float*)(wsb + o_t1d);
  float* t1dn   = (float*)(wsb + o_t1dn);
  int*   cntb   = (int*)(wsb + o_cnt);
  int*   baseb  = (int*)(wsb + o_base);
  int*   curb   = (int*)(wsb + o_cur);
  int*   ordb   = (int*)(wsb + o_ord);
  bf16*  w_in_b = (bf16*)(wsb + o_wib);
  bf16*  w_out_b= (bf16*)(wsb + o_wob);
  bf16*  w_fc_b = (bf16*)(wsb + o_wfb);
  bf16*  w_pj_b = (bf16*)(wsb + o_wpb);
  bf16*  wa1_b  = (bf16*)(wsb + o_wa1b);
  bf16*  wa2_b  = (bf16*)(wsb + o_wa2b);
  bf16*  wat_b  = (bf16*)(wsb + o_watb);
  float* b_in_f = (float*)(wsb + o_bib);
  float* b_fc_f = (float*)(wsb + o_bfb);
  float* b_at_f = (float*)(wsb + o_bab);
  bf16*  fc_bf  = (bf16*)(wsb + o_qkv);  // qkv+Vt dead after attention
  bf16*  ffn_bf = (bf16*)(wsb + o_obf);  // o_bf dead after out-proj

  // ---- weight prep: fold LN affine into W and bias ----
  scalecvt_kernel<<<dim3((3 * CCH * CCH / 4 + 255) / 256, 1), 256, 0, stream>>>(
      w_in, ln1_g, 0, w_in_b, 3 * CCH * CCH);
  foldbias_kernel<<<dim3(3 * CCH, 1), 64, 0, stream>>>(w_in, b_in, ln1_b, 0, b_in_f);
  scalecvt_kernel<<<dim3((4 * CCH * CCH / 4 + 255) / 256, 1), 256, 0, stream>>>(
      w_fc, ln2_g, 0, w_fc_b, 4 * CCH * CCH);
  foldbias_kernel<<<dim3(4 * CCH, 1), 64, 0, stream>>>(w_fc, b_fc, ln2_b, 0, b_fc_f);
  scalecvt_kernel<<<dim3((CCH * CCH / 4 + 255) / 256, NSUP), 256, 0, stream>>>(
      w_attn1, gn3, CCH, wat_b, CCH * CCH);
  foldbias_kernel<<<dim3(CCH, NSUP), 64, 0, stream>>>(w_attn1, b_attn1, bn3, CCH, b_at_f);
  tobf16_kernel<<<(CCH * CCH / 4 + 255) / 256, 256, 0, stream>>>(w_out, w_out_b, CCH * CCH);
  tobf16_kernel<<<(CCH * 4 * CCH / 4 + 255) / 256, 256, 0, stream>>>(w_proj, w_pj_b, CCH * 4 * CCH);
  tobf16_kernel<<<(AAD * CCH / 4 + 255) / 256, 256, 0, stream>>>(wa1, wa1_b, AAD * CCH);
  tobf16_kernel<<<(CCH * AAD / 4 + 255) / 256, 256, 0, stream>>>(wa2, wa2_b, CCH * AAD);
  // counting sort of flat_grid_index (static per call)
  hist0_kernel<<<(NSUP * SEG2 + 255) / 256, 256, 0, stream>>>(cntb);
  hist_kernel<<<(NSUP * NFEAT + 255) / 256, 256, 0, stream>>>(fgi, cntb);
  scan_kernel<<<NSUP, 256, 0, stream>>>(cntb, baseb, curb);
  place_kernel<<<(NSUP * NFEAT + 255) / 256, 256, 0, stream>>>(fgi, curb, ordb);

  // 1) plain norm(x) -> h_bf   (gamma folded into w_in)
  norm_kernel<<<NTOK, 128, 0, stream>>>(x_in, h_bf, 0);
  // 2) qkv = norm(x) @ w_in'^T + b_in'
  mgemm_kernel<2, 2><<<dim3(9, 65, 1), 256, 0, stream>>>(
      h_bf, CCH, 0, w_in_b, CCH, 0, nullptr, 0, 0, qkv_bf, 3 * CCH, 0,
      NTOK, 3 * CCH, CCH, b_in_f, 0, 0, 1.0f, nullptr, 0, nullptr, 0, 0, nullptr, 0);
  // 3) V transpose + flash attention
  vtrans_kernel<<<dim3(SEQP / 64, NB * NHEAD), 256, 0, stream>>>(qkv_bf, Vt);
  flash_kernel<<<dim3(SEQP / 64, NB * NHEAD), 256, 0, stream>>>(qkv_bf, Vt, o_bf);
  // 4) x1 = x + o @ w_out^T + b_out
  mgemm_kernel<2, 2><<<dim3(3, 65, 1), 256, 0, stream>>>(
      o_bf, CCH, 0, w_out_b, CCH, 0, x1, CCH, 0, nullptr, 0, 0,
      NTOK, CCH, CCH, b_out, 0, 0, 1.0f, nullptr, 0, x_in, CCH, 0, nullptr, 0);
  // 5) plain norm(x1) -> h_bf
  norm_kernel<<<NTOK, 128, 0, stream>>>(x1, h_bf, 0);
  // 6) fc = quick_gelu(norm @ w_fc'^T + b_fc')
  mgemm_kernel<2, 2><<<dim3(12, 65, 1), 256, 0, stream>>>(
      h_bf, CCH, 0, w_fc_b, CCH, 0, nullptr, 0, 0, fc_bf, 4 * CCH, 0,
      NTOK, 4 * CCH, CCH, b_fc_f, 0, 1, 1.0f, nullptr, 0, nullptr, 0, 0, nullptr, 0);
  // 7) x_ffn = fc @ w_proj^T + b_proj
  mgemm_kernel<2, 2><<<dim3(3, 65, 1), 256, 0, stream>>>(
      fc_bf, 4 * CCH, 0, w_pj_b, 4 * CCH, 0, ffn, CCH, 0, ffn_bf, CCH, 0,
      NTOK, CCH, 4 * CCH, b_proj, 0, 0, 1.0f, nullptr, 0, nullptr, 0, 0, nullptr, 0);
  // 8) t = quick_gelu(x_ffn @ wa1^T + ba1)
  mgemm_kernel<4, 1><<<dim3(1, 33, 1), 256, 0, stream>>>(
      ffn_bf, CCH, 0, wa1_b, CCH, 0, nullptr, 0, 0, t_bf, AAD, 0,
      NTOK, AAD, CCH, ba1, 0, 1, 1.0f, nullptr, 0, nullptr, 0, 0, nullptr, 0);
  // 9) x2 = x1 + x_ffn + 0.5*(t @ wa2^T + ba2)
  mgemm_kernel<2, 2><<<dim3(3, 65, 1), 256, 0, stream>>>(
      t_bf, AAD, 0, wa2_b, AAD, 0, x2, CCH, 0, nullptr, 0, 0,
      NTOK, CCH, AAD, ba2, 0, 0, 0.5f, nullptr, 0, x1, CCH, 0, ffn, CCH);
  // 10) cluster pooling -> BN+gelu table t3
  seg1_kernel<<<MSEG, 128, 0, stream>>>(x2, sorted_idx, seg_id, s3);
  bnstats_kernel<<<dim3(CCH, 1), 256, 0, stream>>>(s3, 0, MSEG, meanb, varb, 0);
  bnapply_kernel<<<dim3(MSEG, 1), 128, 0, stream>>>(s3, 0, meanb, varb, 0,
      g3, b3, 0, t3, 0, t3n, 0);
  // 11) branches: shared plain norm of x2, z-batched GEMM (gamma folded) -> fx
  norm_kernel<<<NFEAT, 128, 0, stream>>>(x2, h_bf, 1);
  mgemm_kernel<2, 2><<<dim3(3, 64, NSUP), 256, 0, stream>>>(
      h_bf, CCH, 0, wat_b, CCH, (long long)CCH * CCH,
      nullptr, 0, 0, fx, CCH, (long long)NFEAT * CCH,
      NFEAT, CCH, CCH, b_at_f, CCH, 0, 1.0f, maskp, NFEAT, x2, CCH, 1, nullptr, 0);
  // 12) gather-based segment max+mean, then BN+gelu
  seg2_kernel<<<dim3(SEG2, NSUP), 128, 0, stream>>>(fx, baseb, cntb, ordb, ssum);
  bnstats_kernel<<<dim3(CCH, NSUP), 256, 0, stream>>>(
      ssum, (long long)SEG2 * CCH, SEG2, meanb, varb, CCH);
  bnapply_kernel<<<dim3(SEG2, NSUP), 128, 0, stream>>>(
      ssum, (long long)SEG2 * CCH, meanb, varb, CCH,
      g1d, b1d, CCH, t1d, (long long)SEG2 * CCH, t1dn, SEG2);
  // 13) cosine weighting + output
  final_kernel<<<NTOK, 128, 0, stream>>>(x2, t3, t3n, t1d, t1dn, cluster, fgi, out);
}